// Round 1
// baseline (6004.016 us; speedup 1.0000x reference)
//
#include <hip/hip_runtime.h>

#define NNODES 25600
#define DEG 16
#define BGRAPHS 8
#define NPG (NNODES / BGRAPHS)   // 3200 nodes per graph
#define FDIM 7
#define HDIM 300
#define LDIM 100

// ---------------------------------------------------------------------------
// K1: layer-0 node projection.
// U[n,h] = b1[h] + sum_f x[n,f] * (W1[f,h] - W1[f+F,h])   (x_i part, bias folded)
// V[n,h] =         sum_f x[n,f] * W1[f+F,h]               (x_j part)
// Edge preact = U[dst] + V[src].
// ---------------------------------------------------------------------------
__global__ __launch_bounds__(256) void proj0_kernel(
    const float* __restrict__ x, const float* __restrict__ W1,
    const float* __restrict__ b1,
    float* __restrict__ U, float* __restrict__ V)
{
    int idx = blockIdx.x * 256 + threadIdx.x;
    if (idx >= NNODES * HDIM) return;
    int n = idx / HDIM;
    int h = idx - n * HDIM;
    float u = b1[h];
    float v = 0.f;
#pragma unroll
    for (int f = 0; f < FDIM; ++f) {
        float xv = x[n * FDIM + f];
        float wa = W1[f * HDIM + h];
        float wb = W1[(f + FDIM) * HDIM + h];
        u = fmaf(xv, wa - wb, u);
        v = fmaf(xv, wb, v);
    }
    U[idx] = u;
    V[idx] = v;
}

// ---------------------------------------------------------------------------
// K3: layer-1 node projection from h0 [N, L] (post-relu).
// Same decomposition, W1 is [2L, H].
// ---------------------------------------------------------------------------
__global__ __launch_bounds__(128) void proj1_kernel(
    const float* __restrict__ hin, const float* __restrict__ W1,
    const float* __restrict__ b1,
    float* __restrict__ U, float* __restrict__ V)
{
    __shared__ float hrow[LDIM];
    int n = blockIdx.x;
    int t = threadIdx.x;
    if (t < LDIM) hrow[t] = hin[(size_t)n * LDIM + t];
    __syncthreads();
    for (int c = t; c < HDIM; c += 128) {
        float u = b1[c];
        float v = 0.f;
#pragma unroll 4
        for (int k = 0; k < LDIM; ++k) {
            float hv = hrow[k];
            float wa = W1[k * HDIM + c];
            float wb = W1[(k + LDIM) * HDIM + c];
            u = fmaf(hv, wa - wb, u);
            v = fmaf(hv, wb, v);
        }
        U[(size_t)n * HDIM + c] = u;
        V[(size_t)n * HDIM + c] = v;
    }
}

// ---------------------------------------------------------------------------
// K2/K4: fused edge MLP + segment-max for ONE node per block (16 edges).
//   Z1[e,:] = relu(U[n,:] + V[src_e,:])                 (LDS, 16x300)
//   Z2[e,:] = relu(Z1 @ W2 + b2)                        (LDS, 16x300)
//   M3[e,:] = Z2 @ W3 + b3                              (regs, 16x100)
//   hout[n,:] = relu(max_e M3[e,:])
// dst is repeat(arange(N),16) by construction -> node n owns edges 16n..16n+15.
// 128 threads; phase-2 thread owns cols {t, t+128, t+256} (48 acc regs);
// Z1/Z2 LDS reads are wave-uniform broadcasts (conflict-free).
// ---------------------------------------------------------------------------
__global__ __launch_bounds__(128) void edge_mlp_kernel(
    const float* __restrict__ U, const float* __restrict__ V,
    const int* __restrict__ src,
    const float* __restrict__ W2, const float* __restrict__ b2,
    const float* __restrict__ W3, const float* __restrict__ b3,
    float* __restrict__ hout)
{
    __shared__ float Z1[DEG][HDIM];   // 19200 B
    __shared__ float Z2[DEG][HDIM];   // 19200 B
    __shared__ int ssrc[DEG];
    int n = blockIdx.x;
    int t = threadIdx.x;
    if (t < DEG) ssrc[t] = src[n * DEG + t];
    __syncthreads();

    // phase 1: build Z1
    const float* up = U + (size_t)n * HDIM;
    for (int e = 0; e < DEG; ++e) {
        const float* vp = V + (size_t)ssrc[e] * HDIM;
        for (int h = t; h < HDIM; h += 128) {
            float z = up[h] + vp[h];
            Z1[e][h] = fmaxf(z, 0.f);
        }
    }
    __syncthreads();

    // phase 2: Z2 = relu(Z1 @ W2 + b2)
    {
        float acc0[DEG], acc1[DEG], acc2[DEG];
#pragma unroll
        for (int e = 0; e < DEG; ++e) { acc0[e] = 0.f; acc1[e] = 0.f; acc2[e] = 0.f; }
        const int c0 = t, c1 = t + 128, c2 = t + 256;
        const bool has2 = (c2 < HDIM);   // t < 44
#pragma unroll 2
        for (int h = 0; h < HDIM; ++h) {
            const float* wrow = W2 + h * HDIM;
            float w0 = wrow[c0];
            float w1 = wrow[c1];
            float w2v = has2 ? wrow[c2] : 0.f;
#pragma unroll
            for (int e = 0; e < DEG; ++e) {
                float z = Z1[e][h];
                acc0[e] = fmaf(z, w0, acc0[e]);
                acc1[e] = fmaf(z, w1, acc1[e]);
                acc2[e] = fmaf(z, w2v, acc2[e]);
            }
        }
        float bb0 = b2[c0], bb1 = b2[c1], bb2 = has2 ? b2[c2] : 0.f;
#pragma unroll
        for (int e = 0; e < DEG; ++e) {
            Z2[e][c0] = fmaxf(acc0[e] + bb0, 0.f);
            Z2[e][c1] = fmaxf(acc1[e] + bb1, 0.f);
            if (has2) Z2[e][c2] = fmaxf(acc2[e] + bb2, 0.f);
        }
    }
    __syncthreads();

    // phase 3: M3 = Z2 @ W3 (+b3), max over e, relu, store
    if (t < LDIM) {
        float acc[DEG];
#pragma unroll
        for (int e = 0; e < DEG; ++e) acc[e] = 0.f;
#pragma unroll 2
        for (int h = 0; h < HDIM; ++h) {
            float w = W3[h * LDIM + t];
#pragma unroll
            for (int e = 0; e < DEG; ++e)
                acc[e] = fmaf(Z2[e][h], w, acc[e]);
        }
        float mx = acc[0];
#pragma unroll
        for (int e = 1; e < DEG; ++e) mx = fmaxf(mx, acc[e]);
        float r = mx + b3[t];
        hout[(size_t)n * LDIM + t] = fmaxf(r, 0.f);
    }
}

// ---------------------------------------------------------------------------
// K5: per-graph pooling. batch = repeat(arange(8), 3200) -> contiguous blocks.
// pooled[g] = [sum(100) | mean(100) | max(100)]
// ---------------------------------------------------------------------------
__global__ __launch_bounds__(512) void pool_kernel(
    const float* __restrict__ h, float* __restrict__ pooled)
{
    int g = blockIdx.x;
    int t = threadIdx.x;
    int f = t & 127;
    int s = t >> 7;        // 4 node-slices
    __shared__ float ssum[4][LDIM];
    __shared__ float smax[4][LDIM];
    if (f < LDIM) {
        float sum = 0.f;
        float mx = -1e30f;
        for (int n = s; n < NPG; n += 4) {
            float v = h[((size_t)g * NPG + n) * LDIM + f];
            sum += v;
            mx = fmaxf(mx, v);
        }
        ssum[s][f] = sum;
        smax[s][f] = mx;
    }
    __syncthreads();
    if (t < LDIM) {
        float s0 = ssum[0][t] + ssum[1][t] + ssum[2][t] + ssum[3][t];
        float m0 = fmaxf(fmaxf(smax[0][t], smax[1][t]), fmaxf(smax[2][t], smax[3][t]));
        pooled[g * 3 * LDIM + t] = s0;
        pooled[g * 3 * LDIM + LDIM + t] = s0 * (1.0f / NPG);
        pooled[g * 3 * LDIM + 2 * LDIM + t] = m0;
    }
}

// ---------------------------------------------------------------------------
// K6: final MLP on pooled [8, 300] -> [8,1]. Single block, trivial cost.
// ---------------------------------------------------------------------------
__global__ __launch_bounds__(128) void final_kernel(
    const float* __restrict__ pooled,
    const float* __restrict__ W1, const float* __restrict__ b1,
    const float* __restrict__ W2, const float* __restrict__ b2,
    const float* __restrict__ W3, const float* __restrict__ b3,
    float* __restrict__ out)
{
    __shared__ float P[BGRAPHS][3 * LDIM];
    __shared__ float T1[BGRAPHS][LDIM];
    __shared__ float T2[BGRAPHS][LDIM];
    int t = threadIdx.x;
    for (int i = t; i < BGRAPHS * 3 * LDIM; i += 128)
        P[i / (3 * LDIM)][i % (3 * LDIM)] = pooled[i];
    __syncthreads();
    for (int i = t; i < BGRAPHS * LDIM; i += 128) {
        int g = i / LDIM, c = i - (i / LDIM) * LDIM;
        float a = b1[c];
        for (int k = 0; k < 3 * LDIM; ++k) a = fmaf(P[g][k], W1[k * LDIM + c], a);
        T1[g][c] = fmaxf(a, 0.f);
    }
    __syncthreads();
    for (int i = t; i < BGRAPHS * LDIM; i += 128) {
        int g = i / LDIM, c = i - (i / LDIM) * LDIM;
        float a = b2[c];
        for (int k = 0; k < LDIM; ++k) a = fmaf(T1[g][k], W2[k * LDIM + c], a);
        T2[g][c] = fmaxf(a, 0.f);
    }
    __syncthreads();
    if (t < BGRAPHS) {
        float a = b3[0];
        for (int k = 0; k < LDIM; ++k) a = fmaf(T2[t][k], W3[k], a);
        out[t] = a;
    }
}

// ---------------------------------------------------------------------------
extern "C" void kernel_launch(void* const* d_in, const int* in_sizes, int n_in,
                              void* d_out, int out_size, void* d_ws, size_t ws_size,
                              hipStream_t stream)
{
    const float* x      = (const float*)d_in[0];
    const int*   src    = (const int*)d_in[1];   // edge_index[0]; dst = e/16 by construction
    const float* l0_W1  = (const float*)d_in[3];
    const float* l0_b1  = (const float*)d_in[4];
    const float* l0_W2  = (const float*)d_in[5];
    const float* l0_b2  = (const float*)d_in[6];
    const float* l0_W3  = (const float*)d_in[7];
    const float* l0_b3  = (const float*)d_in[8];
    const float* l1_W1  = (const float*)d_in[9];
    const float* l1_b1  = (const float*)d_in[10];
    const float* l1_W2  = (const float*)d_in[11];
    const float* l1_b2  = (const float*)d_in[12];
    const float* l1_W3  = (const float*)d_in[13];
    const float* l1_b3  = (const float*)d_in[14];
    const float* lin_W1 = (const float*)d_in[15];
    const float* lin_b1 = (const float*)d_in[16];
    const float* lin_W2 = (const float*)d_in[17];
    const float* lin_b2 = (const float*)d_in[18];
    const float* lin_W3 = (const float*)d_in[19];
    const float* lin_b3 = (const float*)d_in[20];
    float* out = (float*)d_out;

    // workspace layout (floats): U[N*300] V[N*300] h0[N*100] h1[N*100] pooled[8*300]
    float* U      = (float*)d_ws;
    float* V      = U + (size_t)NNODES * HDIM;
    float* h0     = V + (size_t)NNODES * HDIM;
    float* h1     = h0 + (size_t)NNODES * LDIM;
    float* pooled = h1 + (size_t)NNODES * LDIM;

    // layer 0
    proj0_kernel<<<(NNODES * HDIM + 255) / 256, 256, 0, stream>>>(x, l0_W1, l0_b1, U, V);
    edge_mlp_kernel<<<NNODES, 128, 0, stream>>>(U, V, src, l0_W2, l0_b2, l0_W3, l0_b3, h0);
    // layer 1
    proj1_kernel<<<NNODES, 128, 0, stream>>>(h0, l1_W1, l1_b1, U, V);
    edge_mlp_kernel<<<NNODES, 128, 0, stream>>>(U, V, src, l1_W2, l1_b2, l1_W3, l1_b3, h1);
    // pooling + head
    pool_kernel<<<BGRAPHS, 512, 0, stream>>>(h1, pooled);
    final_kernel<<<1, 128, 0, stream>>>(pooled, lin_W1, lin_b1, lin_W2, lin_b2, lin_W3, lin_b3, out);
}

// Round 2
// 950.487 us; speedup vs baseline: 6.3168x; 6.3168x over previous
//
#include <hip/hip_runtime.h>

#define NNODES 25600
#define DEG 16
#define BGRAPHS 8
#define NPG (NNODES / BGRAPHS)   // 3200
#define FDIM 7
#define HDIM 300
#define LDIM 100
#define HP 320                   // padded H (K and N of GEMM1, K of GEMM2)
#define NT1 20                   // GEMM1 N tiles (320/16)
#define KS1 10                   // GEMM1 K steps (320/32)
#define NT2 7                    // GEMM2 N tiles (112/16), cols >=100 masked
#define KS2 10                   // GEMM2 K steps (320/32)

typedef __attribute__((ext_vector_type(8))) short short8;
typedef __attribute__((ext_vector_type(4))) float floatx4;

union U16x8 { uint4 v; unsigned short s[8]; };

__device__ __forceinline__ float bf2f(unsigned short h) {
    return __uint_as_float(((unsigned)h) << 16);
}
__device__ __forceinline__ unsigned short f2bf(float f) {
    unsigned u = __float_as_uint(f);
    u += 0x7FFFu + ((u >> 16) & 1u);   // RNE
    return (unsigned short)(u >> 16);
}

// ---------------------------------------------------------------------------
// Pack W [Kreal x Nreal] fp32 row-major -> bf16 B-fragment order:
// out[((nt*KS + ks)*64 + lane)*8 + j] = W[k][n], k=32ks+8*(lane>>4)+j, n=16nt+(lane&15)
// zero padded outside real dims.
// ---------------------------------------------------------------------------
__global__ __launch_bounds__(256) void pack_w_kernel(
    const float* __restrict__ W, int Kreal, int Nreal, int Ntiles, int total,
    unsigned short* __restrict__ out)
{
    int idx = blockIdx.x * 256 + threadIdx.x;
    if (idx >= total) return;
    int j = idx & 7;
    int lane = (idx >> 3) & 63;
    int ks = (idx >> 9) % KS1;          // KS1 == KS2 == 10
    int nt = idx / (KS1 * 512);
    int k = ks * 32 + ((lane >> 4) << 3) + j;
    int n = nt * 16 + (lane & 15);
    float v = (k < Kreal && n < Nreal) ? W[k * Nreal + n] : 0.f;
    out[idx] = f2bf(v);
}

__global__ void pack_bias_kernel(const float* __restrict__ b2a,
                                 const float* __restrict__ b2b,
                                 float* __restrict__ o0, float* __restrict__ o1)
{
    int t = threadIdx.x;
    if (t < HP) {
        o0[t] = (t < HDIM) ? b2a[t] : 0.f;
        o1[t] = (t < HDIM) ? b2b[t] : 0.f;
    }
}

// ---------------------------------------------------------------------------
// proj0: x [N,7] fp32 -> U,V bf16 [N,HP] (zero-padded cols 300..319)
// U = x @ (W1a - W1b) + b1 ; V = x @ W1b   (W1 is [14,300])
// ---------------------------------------------------------------------------
__global__ __launch_bounds__(256) void proj0_kernel(
    const float* __restrict__ x, const float* __restrict__ W1,
    const float* __restrict__ b1,
    unsigned short* __restrict__ U, unsigned short* __restrict__ V)
{
    int idx = blockIdx.x * 256 + threadIdx.x;
    if (idx >= NNODES * HP) return;
    int n = idx / HP;
    int h = idx - n * HP;
    float u = 0.f, v = 0.f;
    if (h < HDIM) {
        u = b1[h];
#pragma unroll
        for (int f = 0; f < FDIM; ++f) {
            float xv = x[n * FDIM + f];
            float wa = W1[f * HDIM + h];
            float wb = W1[(f + FDIM) * HDIM + h];
            u = fmaf(xv, wa - wb, u);
            v = fmaf(xv, wb, v);
        }
    }
    U[idx] = f2bf(u);
    V[idx] = f2bf(v);
}

// ---------------------------------------------------------------------------
// proj1: h [N,100] fp32 -> U,V bf16 [N,HP]; W1 is [200,300]
// ---------------------------------------------------------------------------
__global__ __launch_bounds__(128) void proj1_kernel(
    const float* __restrict__ hin, const float* __restrict__ W1,
    const float* __restrict__ b1,
    unsigned short* __restrict__ U, unsigned short* __restrict__ V)
{
    __shared__ float hrow[LDIM];
    int n = blockIdx.x;
    int t = threadIdx.x;
    if (t < LDIM) hrow[t] = hin[(size_t)n * LDIM + t];
    __syncthreads();
    for (int c = t; c < HP; c += 128) {
        float u = 0.f, v = 0.f;
        if (c < HDIM) {
            u = b1[c];
#pragma unroll 4
            for (int k = 0; k < LDIM; ++k) {
                float hv = hrow[k];
                float wa = W1[k * HDIM + c];
                float wb = W1[(k + LDIM) * HDIM + c];
                u = fmaf(hv, wa - wb, u);
                v = fmaf(hv, wb, v);
            }
        }
        U[(size_t)n * HP + c] = f2bf(u);
        V[(size_t)n * HP + c] = f2bf(v);
    }
}

// ---------------------------------------------------------------------------
// Fused edge MLP + segment-max, MFMA version. Block = 4 nodes = 64 edge rows,
// 256 threads = 4 waves.
//   Z1[64, 320] = relu(U[dst] + V[src])     staged in LDS in A-frag order
//   C1 = Z1 @ PB2 (+b2p, relu) -> Z2 chunk (A-frag order, 64 cols at a time)
//   C2 += Z2chunk @ PB3chunk   (pipelined over 5 chunks, acc in VGPRs)
//   hout[node, c] = relu(max_e C2 + b3)
// Wave w: mw=w&1 -> Mtiles {2mw,2mw+1}; nw=w>>1 -> GEMM1 Ntile pair per chunk,
// GEMM2 Ntiles {0..3} (nw=0) / {4..6} (nw=1).
// ---------------------------------------------------------------------------
__global__ __launch_bounds__(256, 3) void edge_mfma_kernel(
    const unsigned short* __restrict__ U, const unsigned short* __restrict__ V,
    const int* __restrict__ src,
    const unsigned short* __restrict__ PB2, const float* __restrict__ b2p,
    const unsigned short* __restrict__ PB3, const float* __restrict__ b3,
    float* __restrict__ hout)
{
    __shared__ unsigned short Z1s[4 * KS1 * 64 * 8];   // 40960 B
    __shared__ unsigned short Z2s[4 * 2 * 64 * 8];     // 8192 B
    __shared__ int sSrc[64];

    const int t = threadIdx.x;
    const int node0 = blockIdx.x * 4;

    if (t < 64) sSrc[t] = src[node0 * 16 + t];
    __syncthreads();

    // ---- phase 1: build Z1 fragments (2560 slots, 10 per thread) ----
#pragma unroll
    for (int i = 0; i < 10; ++i) {
        int s = t + 256 * i;
        int lane = s & 63;
        int ks = (s >> 6) % KS1;
        int mt = s / (KS1 * 64);           // 0..3 == node_local
        int m = mt * 16 + (lane & 15);     // edge row in block
        int k0 = ks * 32 + ((lane >> 4) << 3);
        int srcn = sSrc[m];
        U16x8 ua, va, oz;
        ua.v = *(const uint4*)(U + (size_t)(node0 + mt) * HP + k0);
        va.v = *(const uint4*)(V + (size_t)srcn * HP + k0);
#pragma unroll
        for (int j = 0; j < 8; ++j) {
            float a = bf2f(ua.s[j]) + bf2f(va.s[j]);
            oz.s[j] = f2bf(fmaxf(a, 0.f));
        }
        *(uint4*)(Z1s + (size_t)s * 8) = oz.v;
    }
    __syncthreads();

    const int w = t >> 6;
    const int lane = t & 63;
    const int mw = w & 1;      // M half
    const int nw = w >> 1;     // N half
    const int quad = lane >> 4;
    const int l15 = lane & 15;

    // GEMM2 accumulators: [mtile local 2][ntile up to 4]
    floatx4 c2[2][4];
#pragma unroll
    for (int a = 0; a < 2; ++a)
#pragma unroll
        for (int b = 0; b < 4; ++b) c2[a][b] = (floatx4){0.f, 0.f, 0.f, 0.f};
    const int ntbase2 = nw ? 4 : 0;
    const int ntcnt2  = nw ? 3 : 4;

    for (int nc = 0; nc < 5; ++nc) {
        // ---- GEMM1: C1[2][2] tiles (Mtiles 2mw,2mw+1 x Ntiles 4nc+2nw,+1) ----
        floatx4 c1[2][2];
#pragma unroll
        for (int a = 0; a < 2; ++a)
#pragma unroll
            for (int b = 0; b < 2; ++b) c1[a][b] = (floatx4){0.f, 0.f, 0.f, 0.f};
        const int ntg0 = nc * 4 + 2 * nw;
#pragma unroll 2
        for (int ks = 0; ks < KS1; ++ks) {
            short8 a0 = *(const short8*)(Z1s + ((size_t)((2 * mw) * KS1 + ks) * 64 + lane) * 8);
            short8 a1 = *(const short8*)(Z1s + ((size_t)((2 * mw + 1) * KS1 + ks) * 64 + lane) * 8);
            short8 b0 = *(const short8*)(PB2 + ((size_t)(ntg0 * KS1 + ks) * 64 + lane) * 8);
            short8 b1 = *(const short8*)(PB2 + ((size_t)((ntg0 + 1) * KS1 + ks) * 64 + lane) * 8);
            c1[0][0] = __builtin_amdgcn_mfma_f32_16x16x32_bf16(a0, b0, c1[0][0], 0, 0, 0);
            c1[0][1] = __builtin_amdgcn_mfma_f32_16x16x32_bf16(a0, b1, c1[0][1], 0, 0, 0);
            c1[1][0] = __builtin_amdgcn_mfma_f32_16x16x32_bf16(a1, b0, c1[1][0], 0, 0, 0);
            c1[1][1] = __builtin_amdgcn_mfma_f32_16x16x32_bf16(a1, b1, c1[1][1], 0, 0, 0);
        }
        // ---- epilogue: +b2, relu, bf16, scatter into Z2 chunk (A-frag order) ----
#pragma unroll
        for (int mtl = 0; mtl < 2; ++mtl) {
            int mt = 2 * mw + mtl;
#pragma unroll
            for (int ntl = 0; ntl < 2; ++ntl) {
                int ntg = ntg0 + ntl;
                int col = ntg * 16 + l15;        // 0..319
                float b2v = b2p[col];
                int kc = col - nc * 64;          // 0..63
                int ks2 = kc >> 5;
                int lane2base = 16 * ((kc >> 3) & 3);
                int j = kc & 7;
#pragma unroll
                for (int r = 0; r < 4; ++r) {
                    int row = quad * 4 + r;      // m & 15
                    float vv = fmaxf(c1[mtl][ntl][r] + b2v, 0.f);
                    Z2s[((size_t)(mt * 2 + ks2) * 64 + (row + lane2base)) * 8 + j] = f2bf(vv);
                }
            }
        }
        __syncthreads();
        // ---- GEMM2 partial: K chunk = 64 (2 Ksteps) ----
#pragma unroll
        for (int ks2 = 0; ks2 < 2; ++ks2) {
            int ksg = nc * 2 + ks2;
            short8 a0 = *(const short8*)(Z2s + ((size_t)((2 * mw) * 2 + ks2) * 64 + lane) * 8);
            short8 a1 = *(const short8*)(Z2s + ((size_t)((2 * mw + 1) * 2 + ks2) * 64 + lane) * 8);
#pragma unroll
            for (int i = 0; i < 4; ++i) {
                if (i < ntcnt2) {
                    int nt2 = ntbase2 + i;
                    short8 b = *(const short8*)(PB3 + ((size_t)(nt2 * KS2 + ksg) * 64 + lane) * 8);
                    c2[0][i] = __builtin_amdgcn_mfma_f32_16x16x32_bf16(a0, b, c2[0][i], 0, 0, 0);
                    c2[1][i] = __builtin_amdgcn_mfma_f32_16x16x32_bf16(a1, b, c2[1][i], 0, 0, 0);
                }
            }
        }
        __syncthreads();
    }

    // ---- final epilogue: max over 16 edges (rows of each 16x16 tile), +b3, relu ----
#pragma unroll
    for (int mtl = 0; mtl < 2; ++mtl) {
        int node = node0 + 2 * mw + mtl;
#pragma unroll
        for (int i = 0; i < 4; ++i) {
            if (i < ntcnt2) {
                int nt2 = ntbase2 + i;
                int col = nt2 * 16 + l15;
                floatx4 a = c2[mtl][i];
                float mx = fmaxf(fmaxf(a[0], a[1]), fmaxf(a[2], a[3]));
                mx = fmaxf(mx, __shfl_xor(mx, 16, 64));
                mx = fmaxf(mx, __shfl_xor(mx, 32, 64));
                if (quad == 0 && col < LDIM)
                    hout[(size_t)node * LDIM + col] = fmaxf(mx + b3[col], 0.f);
            }
        }
    }
}

// ---------------------------------------------------------------------------
// pool partials: 200 blocks (8 graphs x 25 slices of 128 nodes)
// ---------------------------------------------------------------------------
__global__ __launch_bounds__(128) void pool1_kernel(
    const float* __restrict__ h, float* __restrict__ part)
{
    int g = blockIdx.x / 25;
    int sl = blockIdx.x % 25;
    int t = threadIdx.x;
    int base = g * NPG + sl * 128;
    if (t < LDIM) {
        float s = 0.f, mx = -1e30f;
        for (int i = 0; i < 128; ++i) {
            float v = h[(size_t)(base + i) * LDIM + t];
            s += v;
            mx = fmaxf(mx, v);
        }
        part[(size_t)blockIdx.x * 200 + t] = s;
        part[(size_t)blockIdx.x * 200 + 100 + t] = mx;
    }
}

// ---------------------------------------------------------------------------
// final: combine partials -> pooled [8,300] -> 3-layer MLP -> out[8]
// ---------------------------------------------------------------------------
__global__ __launch_bounds__(256) void final_kernel(
    const float* __restrict__ part,
    const float* __restrict__ W1, const float* __restrict__ b1,
    const float* __restrict__ W2, const float* __restrict__ b2,
    const float* __restrict__ W3, const float* __restrict__ b3,
    float* __restrict__ out)
{
    __shared__ float P[BGRAPHS][3 * LDIM];
    __shared__ float T1[BGRAPHS][LDIM];
    __shared__ float T2[BGRAPHS][LDIM];
    int t = threadIdx.x;
    for (int i = t; i < BGRAPHS * LDIM; i += 256) {
        int g = i / LDIM, f = i - (i / LDIM) * LDIM;
        float s = 0.f, mx = -1e30f;
        for (int sl = 0; sl < 25; ++sl) {
            s += part[(size_t)(g * 25 + sl) * 200 + f];
            mx = fmaxf(mx, part[(size_t)(g * 25 + sl) * 200 + 100 + f]);
        }
        P[g][f] = s;
        P[g][LDIM + f] = s * (1.0f / NPG);
        P[g][2 * LDIM + f] = mx;
    }
    __syncthreads();
    for (int i = t; i < BGRAPHS * LDIM; i += 256) {
        int g = i / LDIM, c = i - (i / LDIM) * LDIM;
        float a = b1[c];
        for (int k = 0; k < 3 * LDIM; ++k) a = fmaf(P[g][k], W1[k * LDIM + c], a);
        T1[g][c] = fmaxf(a, 0.f);
    }
    __syncthreads();
    for (int i = t; i < BGRAPHS * LDIM; i += 256) {
        int g = i / LDIM, c = i - (i / LDIM) * LDIM;
        float a = b2[c];
        for (int k = 0; k < LDIM; ++k) a = fmaf(T1[g][k], W2[k * LDIM + c], a);
        T2[g][c] = fmaxf(a, 0.f);
    }
    __syncthreads();
    if (t < BGRAPHS) {
        float a = b3[0];
        for (int k = 0; k < LDIM; ++k) a = fmaf(T2[t][k], W3[k], a);
        out[t] = a;
    }
}

// ---------------------------------------------------------------------------
extern "C" void kernel_launch(void* const* d_in, const int* in_sizes, int n_in,
                              void* d_out, int out_size, void* d_ws, size_t ws_size,
                              hipStream_t stream)
{
    const float* x      = (const float*)d_in[0];
    const int*   src    = (const int*)d_in[1];
    const float* l0_W1  = (const float*)d_in[3];
    const float* l0_b1  = (const float*)d_in[4];
    const float* l0_W2  = (const float*)d_in[5];
    const float* l0_b2  = (const float*)d_in[6];
    const float* l0_W3  = (const float*)d_in[7];
    const float* l0_b3  = (const float*)d_in[8];
    const float* l1_W1  = (const float*)d_in[9];
    const float* l1_b1  = (const float*)d_in[10];
    const float* l1_W2  = (const float*)d_in[11];
    const float* l1_b2  = (const float*)d_in[12];
    const float* l1_W3  = (const float*)d_in[13];
    const float* l1_b3  = (const float*)d_in[14];
    const float* lin_W1 = (const float*)d_in[15];
    const float* lin_b1 = (const float*)d_in[16];
    const float* lin_W2 = (const float*)d_in[17];
    const float* lin_b2 = (const float*)d_in[18];
    const float* lin_W3 = (const float*)d_in[19];
    const float* lin_b3 = (const float*)d_in[20];
    float* out = (float*)d_out;

    // workspace layout (bytes, all 16B aligned)
    char* p = (char*)d_ws;
    unsigned short* U     = (unsigned short*)p;               p += (size_t)NNODES * HP * 2;   // 16,384,000
    unsigned short* Vb    = (unsigned short*)p;               p += (size_t)NNODES * HP * 2;
    float* h0             = (float*)p;                        p += (size_t)NNODES * LDIM * 4; // 10,240,000
    float* h1             = (float*)p;                        p += (size_t)NNODES * LDIM * 4;
    unsigned short* PB2_0 = (unsigned short*)p;               p += (size_t)NT1 * KS1 * 512 * 2;   // 204,800
    unsigned short* PB3_0 = (unsigned short*)p;               p += (size_t)NT2 * KS2 * 512 * 2;   // 71,680
    unsigned short* PB2_1 = (unsigned short*)p;               p += (size_t)NT1 * KS1 * 512 * 2;
    unsigned short* PB3_1 = (unsigned short*)p;               p += (size_t)NT2 * KS2 * 512 * 2;
    float* b2p_0          = (float*)p;                        p += HP * 4;
    float* b2p_1          = (float*)p;                        p += HP * 4;
    float* part           = (float*)p;                        p += (size_t)200 * 200 * 4;

    // weight packing (tiny, idempotent)
    {
        int tot2 = NT1 * KS1 * 512;
        int tot3 = NT2 * KS2 * 512;
        pack_w_kernel<<<(tot2 + 255) / 256, 256, 0, stream>>>(l0_W2, HDIM, HDIM, NT1, tot2, PB2_0);
        pack_w_kernel<<<(tot3 + 255) / 256, 256, 0, stream>>>(l0_W3, HDIM, LDIM, NT2, tot3, PB3_0);
        pack_w_kernel<<<(tot2 + 255) / 256, 256, 0, stream>>>(l1_W2, HDIM, HDIM, NT1, tot2, PB2_1);
        pack_w_kernel<<<(tot3 + 255) / 256, 256, 0, stream>>>(l1_W3, HDIM, LDIM, NT2, tot3, PB3_1);
        pack_bias_kernel<<<1, HP, 0, stream>>>(l0_b2, l1_b2, b2p_0, b2p_1);
    }

    // layer 0
    proj0_kernel<<<(NNODES * HP + 255) / 256, 256, 0, stream>>>(x, l0_W1, l0_b1, U, Vb);
    edge_mfma_kernel<<<NNODES / 4, 256, 0, stream>>>(U, Vb, src, PB2_0, b2p_0, PB3_0, l0_b3, h0);
    // layer 1
    proj1_kernel<<<NNODES, 128, 0, stream>>>(h0, l1_W1, l1_b1, U, Vb);
    edge_mfma_kernel<<<NNODES / 4, 256, 0, stream>>>(U, Vb, src, PB2_1, b2p_1, PB3_1, l1_b3, h1);
    // pooling + head
    pool1_kernel<<<200, 128, 0, stream>>>(h1, part);
    final_kernel<<<1, 256, 0, stream>>>(part, lin_W1, lin_b1, lin_W2, lin_b2, lin_W3, lin_b3, out);
}

// Round 3
// 699.309 us; speedup vs baseline: 8.5856x; 1.3592x over previous
//
#include <hip/hip_runtime.h>

#define NNODES 25600
#define DEG 16
#define BGRAPHS 8
#define NPG (NNODES / BGRAPHS)   // 3200
#define FDIM 7
#define HDIM 300
#define LDIM 100
#define HP 320                   // padded H
#define NT1 20                   // GEMM1 N tiles (320/16)
#define KS1 10                   // GEMM1 K steps (320/32)
#define NT2 7                    // GEMM2 N tiles (112/16)
#define KS2 10                   // GEMM2 K steps (320/32)
#define H0W 128                  // h0 bf16 padded width (K of proj1)

typedef __attribute__((ext_vector_type(8))) short short8;
typedef __attribute__((ext_vector_type(4))) float floatx4;

union U16x8 { uint4 v; unsigned short s[8]; };

__device__ __forceinline__ float bf2f(unsigned short h) {
    return __uint_as_float(((unsigned)h) << 16);
}
__device__ __forceinline__ unsigned short f2bf(float f) {
    unsigned u = __float_as_uint(f);
    u += 0x7FFFu + ((u >> 16) & 1u);   // RNE
    return (unsigned short)(u >> 16);
}

// ---------------------------------------------------------------------------
// B-fragment packing: out[((nt*KS+ks)*64+lane)*8+j] = W[k][n],
// k = 32ks + 8*(lane>>4) + j, n = 16nt + (lane&15); zero outside real dims.
// ---------------------------------------------------------------------------
__device__ __forceinline__ unsigned short packB(const float* W, int Kreal, int Nreal,
                                                int KS, int rel)
{
    int j = rel & 7, lane = (rel >> 3) & 63, rem = rel >> 9;
    int ks = rem % KS, nt = rem / KS;
    int k = ks * 32 + ((lane >> 4) << 3) + j;
    int n = nt * 16 + (lane & 15);
    float v = (k < Kreal && n < Nreal) ? W[k * Nreal + n] : 0.f;
    return f2bf(v);
}

// proj effective weights: Weff[k][n] (k<Ksub):
//   n<320 (U part):  n<300 ? W1[k][n] - W1[k+Ksub][n] : 0
//   n>=320 (V part): (n-320)<300 ? W1[k+Ksub][n-320] : 0
__device__ __forceinline__ unsigned short packProjW(const float* W1, int Ksub,
                                                    int KS, int rel)
{
    int j = rel & 7, lane = (rel >> 3) & 63, rem = rel >> 9;
    int ks = rem % KS, nt = rem / KS;
    int k = ks * 32 + ((lane >> 4) << 3) + j;
    int n = nt * 16 + (lane & 15);
    float v = 0.f;
    if (k < Ksub) {
        if (n < HP) { if (n < HDIM) v = W1[k * HDIM + n] - W1[(k + Ksub) * HDIM + n]; }
        else { int m = n - HP; if (m < HDIM) v = W1[(k + Ksub) * HDIM + m]; }
    }
    return f2bf(v);
}

#define S0 102400   // PB2_0
#define S1 102400   // PB2_1
#define S2 35840    // PB3_0
#define S3 35840    // PB3_1
#define S4 81920    // PW1 (40 nt x 4 ks)
#define S5 20480    // PW0 (40 nt x 1 ks)
#define S6 1920     // biases
#define PACK_TOTAL (S0+S1+S2+S3+S4+S5+S6)

__global__ __launch_bounds__(256) void pack_all_kernel(
    const float* __restrict__ l0_W1, const float* __restrict__ l0_b1,
    const float* __restrict__ l0_W2, const float* __restrict__ l0_b2,
    const float* __restrict__ l0_W3,
    const float* __restrict__ l1_W1, const float* __restrict__ l1_b1,
    const float* __restrict__ l1_W2, const float* __restrict__ l1_b2,
    const float* __restrict__ l1_W3,
    unsigned short* __restrict__ PB2_0, unsigned short* __restrict__ PB2_1,
    unsigned short* __restrict__ PB3_0, unsigned short* __restrict__ PB3_1,
    unsigned short* __restrict__ PW1,  unsigned short* __restrict__ PW0,
    float* __restrict__ b2p_0, float* __restrict__ b2p_1,
    float* __restrict__ bp1,   float* __restrict__ bp0)
{
    int idx = blockIdx.x * 256 + threadIdx.x;
    if (idx >= PACK_TOTAL) return;
    if (idx < S0) { PB2_0[idx] = packB(l0_W2, HDIM, HDIM, KS1, idx); return; }
    idx -= S0;
    if (idx < S1) { PB2_1[idx] = packB(l1_W2, HDIM, HDIM, KS1, idx); return; }
    idx -= S1;
    if (idx < S2) { PB3_0[idx] = packB(l0_W3, HDIM, LDIM, KS2, idx); return; }
    idx -= S2;
    if (idx < S3) { PB3_1[idx] = packB(l1_W3, HDIM, LDIM, KS2, idx); return; }
    idx -= S3;
    if (idx < S4) { PW1[idx] = packProjW(l1_W1, LDIM, 4, idx); return; }
    idx -= S4;
    if (idx < S5) { PW0[idx] = packProjW(l0_W1, FDIM, 1, idx); return; }
    idx -= S5;
    // biases
    if (idx < 320)       { b2p_0[idx] = (idx < HDIM) ? l0_b2[idx] : 0.f; return; }
    if (idx < 640)       { int n = idx - 320; b2p_1[n] = (n < HDIM) ? l1_b2[n] : 0.f; return; }
    if (idx < 1280)      { int n = idx - 640; bp1[n] = (n < HDIM) ? l1_b1[n] : 0.f; return; }
    { int n = idx - 1280; bp0[n] = (n < HDIM) ? l0_b1[n] : 0.f; }
}

// ---------------------------------------------------------------------------
// proj GEMM: rows x Weff -> U | V  (bf16 [N,320] each, bias added, no relu).
// M=64 rows/block (4 mtiles), N=640 (40 ntiles), K = KS*32.
// Wave w owns ntiles w*10 .. w*10+9 processed in 2 groups of 5 (C regs 5x4 tiles).
// A_IS_X: A = x fp32 [N,7] (KS=1, zero-padded); else A = h0 bf16 [N,128] (KS=4).
// ---------------------------------------------------------------------------
template<int KS, bool A_IS_X>
__global__ __launch_bounds__(256) void proj_gemm_kernel(
    const void* __restrict__ Asrc, const unsigned short* __restrict__ PW,
    const float* __restrict__ bp,
    unsigned short* __restrict__ U, unsigned short* __restrict__ Vb)
{
    __shared__ unsigned short As[4 * KS * 64 * 8];
    const int t = threadIdx.x;
    const int row0 = blockIdx.x * 64;

    if constexpr (A_IS_X) {
        const float* x = (const float*)Asrc;
        int lane = t & 63, mt = t >> 6;
        int quad = lane >> 4;
        int grow = row0 + mt * 16 + (lane & 15);
        U16x8 oz;
#pragma unroll
        for (int j = 0; j < 8; ++j) {
            int k = quad * 8 + j;
            oz.s[j] = (k < FDIM) ? f2bf(x[grow * FDIM + k]) : (unsigned short)0;
        }
        *(uint4*)(As + t * 8) = oz.v;
    } else {
        const unsigned short* h = (const unsigned short*)Asrc;
#pragma unroll
        for (int i = 0; i < 4; ++i) {
            int s = t + 256 * i;
            int lane = s & 63;
            int ks = (s >> 6) % KS;
            int mt = s / (KS * 64);
            int grow = row0 + mt * 16 + (lane & 15);
            int k0 = ks * 32 + ((lane >> 4) << 3);
            *(uint4*)(As + s * 8) = *(const uint4*)(h + (size_t)grow * H0W + k0);
        }
    }
    __syncthreads();

    const int w = t >> 6, lane = t & 63, quad = lane >> 4, l15 = lane & 15;

    for (int g = 0; g < 2; ++g) {
        const int ntb = w * 10 + g * 5;
        floatx4 c[5][4];
#pragma unroll
        for (int i = 0; i < 5; ++i)
#pragma unroll
            for (int mt = 0; mt < 4; ++mt) c[i][mt] = (floatx4){0.f, 0.f, 0.f, 0.f};
#pragma unroll
        for (int ks = 0; ks < KS; ++ks) {
            short8 a[4];
#pragma unroll
            for (int mt = 0; mt < 4; ++mt)
                a[mt] = *(const short8*)(As + ((size_t)(mt * KS + ks) * 64 + lane) * 8);
#pragma unroll
            for (int i = 0; i < 5; ++i) {
                short8 b = *(const short8*)(PW + ((size_t)((ntb + i) * KS + ks) * 64 + lane) * 8);
#pragma unroll
                for (int mt = 0; mt < 4; ++mt)
                    c[i][mt] = __builtin_amdgcn_mfma_f32_16x16x32_bf16(a[mt], b, c[i][mt], 0, 0, 0);
            }
        }
        // epilogue: +bias, bf16, write U (cols<320) / V
#pragma unroll
        for (int i = 0; i < 5; ++i) {
            int col = (ntb + i) * 16 + l15;
            float bb = bp[col];
#pragma unroll
            for (int mt = 0; mt < 4; ++mt) {
#pragma unroll
                for (int r = 0; r < 4; ++r) {
                    int grow = row0 + mt * 16 + quad * 4 + r;
                    unsigned short val = f2bf(c[i][mt][r] + bb);
                    if (col < HP) U[(size_t)grow * HP + col] = val;
                    else          Vb[(size_t)grow * HP + (col - HP)] = val;
                }
            }
        }
    }
}

// ---------------------------------------------------------------------------
// Fused edge MLP + segment-max. Block = 4 nodes (M=64), 256 threads / 4 waves.
// Waves split N only (no B duplication). GEMM2 K-chunked in 2 halves of 160.
//   Z1[64,320] bf16 A-frag in LDS (40 KB)
//   per half: GEMM1 (C1 regs 4mt x <=3nt) -> Z2 chunk (20.5 KB LDS, A-frag)
//             GEMM2 accumulate into C2 regs (4mt x <=2nt2)
//   epilogue: max over 16 edge rows, +b3, relu.
// OUT_BF16: write h0 bf16 [N,128] zero-padded; else fp32 [N,100].
// ---------------------------------------------------------------------------
template<bool OUT_BF16>
__global__ __launch_bounds__(256, 2) void edge_mfma_kernel(
    const unsigned short* __restrict__ U, const unsigned short* __restrict__ V,
    const int* __restrict__ src,
    const unsigned short* __restrict__ PB2, const float* __restrict__ b2p,
    const unsigned short* __restrict__ PB3, const float* __restrict__ b3,
    void* __restrict__ hout)
{
    __shared__ unsigned short Z1s[4 * KS1 * 64 * 8];   // 40960 B
    __shared__ unsigned short Z2s[4 * 5 * 64 * 8];     // 20480 B (K-half of GEMM2)
    __shared__ int sSrc[64];

    const int t = threadIdx.x;
    const int node0 = blockIdx.x * 4;

    if (t < 64) sSrc[t] = src[node0 * 16 + t];
    __syncthreads();

    // ---- Z1 build: 2560 A-frag slots, 10 per thread ----
#pragma unroll
    for (int i = 0; i < 10; ++i) {
        int s = t + 256 * i;
        int lane = s & 63;
        int ks = (s >> 6) % KS1;
        int mt = s / (KS1 * 64);
        int m = mt * 16 + (lane & 15);
        int k0 = ks * 32 + ((lane >> 4) << 3);
        int srcn = sSrc[m];
        U16x8 ua, va, oz;
        ua.v = *(const uint4*)(U + (size_t)(node0 + mt) * HP + k0);
        va.v = *(const uint4*)(V + (size_t)srcn * HP + k0);
#pragma unroll
        for (int j = 0; j < 8; ++j) {
            float a = bf2f(ua.s[j]) + bf2f(va.s[j]);
            oz.s[j] = f2bf(fmaxf(a, 0.f));
        }
        *(uint4*)(Z1s + (size_t)s * 8) = oz.v;
    }
    __syncthreads();

    const int w = t >> 6;
    const int lane = t & 63;
    const int quad = lane >> 4;
    const int l15 = lane & 15;

    // GEMM2 N ownership: {2,2,2,1} ntiles
    const int nt2Base = w * 2;
    const int nt2Cnt  = (w < 3) ? 2 : 1;
    floatx4 c2[4][2];
#pragma unroll
    for (int mt = 0; mt < 4; ++mt)
#pragma unroll
        for (int i = 0; i < 2; ++i) c2[mt][i] = (floatx4){0.f, 0.f, 0.f, 0.f};

    for (int h = 0; h < 2; ++h) {
        // per-half GEMM1 N ownership (balanced across halves):
        // h0: counts {3,3,2,2} bases {0,3,6,8}; h1: counts {2,2,3,3} bases {0,2,4,7}
        const int cnt = (h == 0) ? ((w < 2) ? 3 : 2) : ((w < 2) ? 2 : 3);
        const int base = (h == 0) ? ((w < 2) ? 3 * w : 6 + 2 * (w - 2))
                                  : ((w < 2) ? 2 * w : 4 + 3 * (w - 2));
        // ---- GEMM1: full K=320, cols of this half ----
        floatx4 c1[4][3];
#pragma unroll
        for (int mt = 0; mt < 4; ++mt)
#pragma unroll
            for (int i = 0; i < 3; ++i) c1[mt][i] = (floatx4){0.f, 0.f, 0.f, 0.f};
#pragma unroll 2
        for (int ks = 0; ks < KS1; ++ks) {
            short8 a[4];
#pragma unroll
            for (int mt = 0; mt < 4; ++mt)
                a[mt] = *(const short8*)(Z1s + ((size_t)(mt * KS1 + ks) * 64 + lane) * 8);
#pragma unroll
            for (int i = 0; i < 3; ++i) {
                if (i < cnt) {
                    int nt = h * 10 + base + i;
                    short8 b = *(const short8*)(PB2 + ((size_t)(nt * KS1 + ks) * 64 + lane) * 8);
#pragma unroll
                    for (int mt = 0; mt < 4; ++mt)
                        c1[mt][i] = __builtin_amdgcn_mfma_f32_16x16x32_bf16(a[mt], b, c1[mt][i], 0, 0, 0);
                }
            }
        }
        // ---- epilogue: +b2, relu, bf16 -> Z2s (A-frag, K-local = 160) ----
#pragma unroll
        for (int i = 0; i < 3; ++i) {
            if (i < cnt) {
                int ntl = base + i;                 // 0..9 within half
                int colg = (h * 10 + ntl) * 16 + l15;
                float b2v = b2p[colg];
                int kc = ntl * 16 + l15;            // 0..159 (K index within half)
                int ks2h = kc >> 5;
                int lane2base = ((kc >> 3) & 3) << 4;
                int j = kc & 7;
#pragma unroll
                for (int mt = 0; mt < 4; ++mt) {
#pragma unroll
                    for (int r = 0; r < 4; ++r) {
                        int row = quad * 4 + r;
                        float vv = fmaxf(c1[mt][i][r] + b2v, 0.f);
                        Z2s[((size_t)(mt * 5 + ks2h) * 64 + (row + lane2base)) * 8 + j] = f2bf(vv);
                    }
                }
            }
        }
        __syncthreads();
        // ---- GEMM2 partial: K-half = 160 (5 ksteps) ----
#pragma unroll
        for (int ks2 = 0; ks2 < 5; ++ks2) {
            int ksg = h * 5 + ks2;
            short8 a[4];
#pragma unroll
            for (int mt = 0; mt < 4; ++mt)
                a[mt] = *(const short8*)(Z2s + ((size_t)(mt * 5 + ks2) * 64 + lane) * 8);
#pragma unroll
            for (int i = 0; i < 2; ++i) {
                if (i < nt2Cnt) {
                    int nt2 = nt2Base + i;
                    short8 b = *(const short8*)(PB3 + ((size_t)(nt2 * KS2 + ksg) * 64 + lane) * 8);
#pragma unroll
                    for (int mt = 0; mt < 4; ++mt)
                        c2[mt][i] = __builtin_amdgcn_mfma_f32_16x16x32_bf16(a[mt], b, c2[mt][i], 0, 0, 0);
                }
            }
        }
        __syncthreads();   // Z2s consumed; safe for next half's epilogue
    }

    // ---- final epilogue: max over 16 edges, +b3, relu, store ----
#pragma unroll
    for (int mt = 0; mt < 4; ++mt) {
        int node = node0 + mt;
#pragma unroll
        for (int i = 0; i < 2; ++i) {
            if (i < nt2Cnt) {
                int col = (nt2Base + i) * 16 + l15;
                floatx4 a = c2[mt][i];
                float mx = fmaxf(fmaxf(a[0], a[1]), fmaxf(a[2], a[3]));
                mx = fmaxf(mx, __shfl_xor(mx, 16, 64));
                mx = fmaxf(mx, __shfl_xor(mx, 32, 64));
                if (quad == 0) {
                    if (OUT_BF16) {
                        unsigned short val = 0;
                        if (col < LDIM) val = f2bf(fmaxf(mx + b3[col], 0.f));
                        ((unsigned short*)hout)[(size_t)node * H0W + col] = val;  // cols 0..111
                    } else {
                        if (col < LDIM)
                            ((float*)hout)[(size_t)node * LDIM + col] = fmaxf(mx + b3[col], 0.f);
                    }
                }
            }
        }
        if (OUT_BF16 && w == 3 && quad == 0)     // pad cols 112..127
            ((unsigned short*)hout)[(size_t)node * H0W + 112 + l15] = 0;
    }
}

// ---------------------------------------------------------------------------
// pool partials: 200 blocks (8 graphs x 25 slices of 128 nodes)
// ---------------------------------------------------------------------------
__global__ __launch_bounds__(128) void pool1_kernel(
    const float* __restrict__ h, float* __restrict__ part)
{
    int g = blockIdx.x / 25;
    int sl = blockIdx.x % 25;
    int t = threadIdx.x;
    int base = g * NPG + sl * 128;
    if (t < LDIM) {
        float s = 0.f, mx = -1e30f;
        for (int i = 0; i < 128; ++i) {
            float v = h[(size_t)(base + i) * LDIM + t];
            s += v;
            mx = fmaxf(mx, v);
        }
        part[(size_t)blockIdx.x * 200 + t] = s;
        part[(size_t)blockIdx.x * 200 + 100 + t] = mx;
    }
}

// ---------------------------------------------------------------------------
// final: combine partials -> pooled [8,300] -> 3-layer MLP -> out[8]
// ---------------------------------------------------------------------------
__global__ __launch_bounds__(256) void final_kernel(
    const float* __restrict__ part,
    const float* __restrict__ W1, const float* __restrict__ b1,
    const float* __restrict__ W2, const float* __restrict__ b2,
    const float* __restrict__ W3, const float* __restrict__ b3,
    float* __restrict__ out)
{
    __shared__ float P[BGRAPHS][3 * LDIM];
    __shared__ float T1[BGRAPHS][LDIM];
    __shared__ float T2[BGRAPHS][LDIM];
    int t = threadIdx.x;
    for (int i = t; i < BGRAPHS * LDIM; i += 256) {
        int g = i / LDIM, f = i - (i / LDIM) * LDIM;
        float s = 0.f, mx = -1e30f;
        for (int sl = 0; sl < 25; ++sl) {
            s += part[(size_t)(g * 25 + sl) * 200 + f];
            mx = fmaxf(mx, part[(size_t)(g * 25 + sl) * 200 + 100 + f]);
        }
        P[g][f] = s;
        P[g][LDIM + f] = s * (1.0f / NPG);
        P[g][2 * LDIM + f] = mx;
    }
    __syncthreads();
    for (int i = t; i < BGRAPHS * LDIM; i += 256) {
        int g = i / LDIM, c = i - (i / LDIM) * LDIM;
        float a = b1[c];
        for (int k = 0; k < 3 * LDIM; ++k) a = fmaf(P[g][k], W1[k * LDIM + c], a);
        T1[g][c] = fmaxf(a, 0.f);
    }
    __syncthreads();
    for (int i = t; i < BGRAPHS * LDIM; i += 256) {
        int g = i / LDIM, c = i - (i / LDIM) * LDIM;
        float a = b2[c];
        for (int k = 0; k < LDIM; ++k) a = fmaf(T1[g][k], W2[k * LDIM + c], a);
        T2[g][c] = fmaxf(a, 0.f);
    }
    __syncthreads();
    if (t < BGRAPHS) {
        float a = b3[0];
        for (int k = 0; k < LDIM; ++k) a = fmaf(T2[t][k], W3[k], a);
        out[t] = a;
    }
}

// ---------------------------------------------------------------------------
extern "C" void kernel_launch(void* const* d_in, const int* in_sizes, int n_in,
                              void* d_out, int out_size, void* d_ws, size_t ws_size,
                              hipStream_t stream)
{
    const float* x      = (const float*)d_in[0];
    const int*   src    = (const int*)d_in[1];
    const float* l0_W1  = (const float*)d_in[3];
    const float* l0_b1  = (const float*)d_in[4];
    const float* l0_W2  = (const float*)d_in[5];
    const float* l0_b2  = (const float*)d_in[6];
    const float* l0_W3  = (const float*)d_in[7];
    const float* l0_b3  = (const float*)d_in[8];
    const float* l1_W1  = (const float*)d_in[9];
    const float* l1_b1  = (const float*)d_in[10];
    const float* l1_W2  = (const float*)d_in[11];
    const float* l1_b2  = (const float*)d_in[12];
    const float* l1_W3  = (const float*)d_in[13];
    const float* l1_b3  = (const float*)d_in[14];
    const float* lin_W1 = (const float*)d_in[15];
    const float* lin_b1 = (const float*)d_in[16];
    const float* lin_W2 = (const float*)d_in[17];
    const float* lin_b2 = (const float*)d_in[18];
    const float* lin_W3 = (const float*)d_in[19];
    const float* lin_b3 = (const float*)d_in[20];
    float* out = (float*)d_out;

    // workspace layout
    char* p = (char*)d_ws;
    unsigned short* U     = (unsigned short*)p;  p += (size_t)NNODES * HP * 2;      // 16.38 MB
    unsigned short* Vb    = (unsigned short*)p;  p += (size_t)NNODES * HP * 2;
    unsigned short* h0b   = (unsigned short*)p;  p += (size_t)NNODES * H0W * 2;     // 6.55 MB
    float* h1             = (float*)p;           p += (size_t)NNODES * LDIM * 4;    // 10.24 MB
    unsigned short* PB2_0 = (unsigned short*)p;  p += (size_t)S0 * 2;
    unsigned short* PB2_1 = (unsigned short*)p;  p += (size_t)S1 * 2;
    unsigned short* PB3_0 = (unsigned short*)p;  p += (size_t)S2 * 2;
    unsigned short* PB3_1 = (unsigned short*)p;  p += (size_t)S3 * 2;
    unsigned short* PW1   = (unsigned short*)p;  p += (size_t)S4 * 2;
    unsigned short* PW0   = (unsigned short*)p;  p += (size_t)S5 * 2;
    float* b2p_0          = (float*)p;           p += HP * 4;
    float* b2p_1          = (float*)p;           p += HP * 4;
    float* bp1            = (float*)p;           p += 640 * 4;
    float* bp0            = (float*)p;           p += 640 * 4;
    float* part           = (float*)p;           p += (size_t)200 * 200 * 4;

    pack_all_kernel<<<(PACK_TOTAL + 255) / 256, 256, 0, stream>>>(
        l0_W1, l0_b1, l0_W2, l0_b2, l0_W3,
        l1_W1, l1_b1, l1_W2, l1_b2, l1_W3,
        PB2_0, PB2_1, PB3_0, PB3_1, PW1, PW0, b2p_0, b2p_1, bp1, bp0);

    // layer 0
    proj_gemm_kernel<1, true><<<NNODES / 64, 256, 0, stream>>>(x, PW0, bp0, U, Vb);
    edge_mfma_kernel<true><<<NNODES / 4, 256, 0, stream>>>(U, Vb, src, PB2_0, b2p_0, PB3_0, l0_b3, h0b);
    // layer 1
    proj_gemm_kernel<4, false><<<NNODES / 64, 256, 0, stream>>>(h0b, PW1, bp1, U, Vb);
    edge_mfma_kernel<false><<<NNODES / 4, 256, 0, stream>>>(U, Vb, src, PB2_1, b2p_1, PB3_1, l1_b3, h1);
    // pooling + head
    pool1_kernel<<<200, 128, 0, stream>>>(h1, part);
    final_kernel<<<1, 256, 0, stream>>>(part, lin_W1, lin_b1, lin_W2, lin_b2, lin_W3, lin_b3, out);
}

// Round 4
// 536.390 us; speedup vs baseline: 11.1934x; 1.3037x over previous
//
#include <hip/hip_runtime.h>

#define NNODES 25600
#define DEG 16
#define BGRAPHS 8
#define NPG (NNODES / BGRAPHS)   // 3200
#define FDIM 7
#define HDIM 300
#define LDIM 100
#define HP 320                   // padded H
#define UVW 640                  // UV row width (U 0..319 | V 320..639)
#define NT1 20                   // GEMM1 N tiles
#define KS1 10                   // GEMM1 K steps
#define NT2 7                    // GEMM2 N tiles (112 cols, >=100 masked)
#define KS2 10                   // GEMM2 K steps
#define H0W 128                  // h0 bf16 padded width
#define SSTR 328                 // proj staging row stride (shorts); 656B = 41*16

typedef __attribute__((ext_vector_type(8))) short short8;
typedef __attribute__((ext_vector_type(4))) float floatx4;

__device__ __forceinline__ float bf2f(unsigned short h) {
    return __uint_as_float(((unsigned)h) << 16);
}
__device__ __forceinline__ unsigned short f2bf(float f) {   // round-half-up (pack path)
    return (unsigned short)((__float_as_uint(f) + 0x8000u) >> 16);
}
// pack two fp32 (lo,hi) -> one dword of two bf16, round-half-up
__device__ __forceinline__ unsigned packbf2(float lo, float hi) {
    unsigned rl = __float_as_uint(lo) + 0x8000u;
    unsigned rh = __float_as_uint(hi) + 0x8000u;
    return __builtin_amdgcn_perm(rh, rl, 0x07060302);
}

// ---------------------------------------------------------------------------
// B-fragment packing: out[((nt*KS+ks)*64+lane)*8+j] = W[k][n]
// ---------------------------------------------------------------------------
__device__ __forceinline__ unsigned short packB(const float* W, int Kreal, int Nreal,
                                                int KS, int rel)
{
    int j = rel & 7, lane = (rel >> 3) & 63, rem = rel >> 9;
    int ks = rem % KS, nt = rem / KS;
    int k = ks * 32 + ((lane >> 4) << 3) + j;
    int n = nt * 16 + (lane & 15);
    float v = (k < Kreal && n < Nreal) ? W[k * Nreal + n] : 0.f;
    return f2bf(v);
}

// proj effective weights Weff[k][n], n<320 = U part (W1a - W1b), n>=320 = V part (W1b)
__device__ __forceinline__ unsigned short packProjW(const float* W1, int Ksub,
                                                    int KS, int rel)
{
    int j = rel & 7, lane = (rel >> 3) & 63, rem = rel >> 9;
    int ks = rem % KS, nt = rem / KS;
    int k = ks * 32 + ((lane >> 4) << 3) + j;
    int n = nt * 16 + (lane & 15);
    float v = 0.f;
    if (k < Ksub) {
        if (n < HP) { if (n < HDIM) v = W1[k * HDIM + n] - W1[(k + Ksub) * HDIM + n]; }
        else { int m = n - HP; if (m < HDIM) v = W1[(k + Ksub) * HDIM + m]; }
    }
    return f2bf(v);
}

#define S0 102400   // PB2_0
#define S1 102400   // PB2_1
#define S2 35840    // PB3_0
#define S3 35840    // PB3_1
#define S4 81920    // PW1 (40 nt x 4 ks)
#define S5 20480    // PW0 (40 nt x 1 ks)
#define S6 1920     // biases
#define PACK_TOTAL (S0+S1+S2+S3+S4+S5+S6)

__global__ __launch_bounds__(256) void pack_all_kernel(
    const float* __restrict__ l0_W1, const float* __restrict__ l0_b1,
    const float* __restrict__ l0_W2, const float* __restrict__ l0_b2,
    const float* __restrict__ l0_W3,
    const float* __restrict__ l1_W1, const float* __restrict__ l1_b1,
    const float* __restrict__ l1_W2, const float* __restrict__ l1_b2,
    const float* __restrict__ l1_W3,
    unsigned short* __restrict__ PB2_0, unsigned short* __restrict__ PB2_1,
    unsigned short* __restrict__ PB3_0, unsigned short* __restrict__ PB3_1,
    unsigned short* __restrict__ PW1,  unsigned short* __restrict__ PW0,
    float* __restrict__ b2p_0, float* __restrict__ b2p_1,
    float* __restrict__ bp1,   float* __restrict__ bp0)
{
    int idx = blockIdx.x * 256 + threadIdx.x;
    if (idx >= PACK_TOTAL) return;
    if (idx < S0) { PB2_0[idx] = packB(l0_W2, HDIM, HDIM, KS1, idx); return; }
    idx -= S0;
    if (idx < S1) { PB2_1[idx] = packB(l1_W2, HDIM, HDIM, KS1, idx); return; }
    idx -= S1;
    if (idx < S2) { PB3_0[idx] = packB(l0_W3, HDIM, LDIM, KS2, idx); return; }
    idx -= S2;
    if (idx < S3) { PB3_1[idx] = packB(l1_W3, HDIM, LDIM, KS2, idx); return; }
    idx -= S3;
    if (idx < S4) { PW1[idx] = packProjW(l1_W1, LDIM, 4, idx); return; }
    idx -= S4;
    if (idx < S5) { PW0[idx] = packProjW(l0_W1, FDIM, 1, idx); return; }
    idx -= S5;
    if (idx < 320)       { b2p_0[idx] = (idx < HDIM) ? l0_b2[idx] : 0.f; return; }
    if (idx < 640)       { int n = idx - 320; b2p_1[n] = (n < HDIM) ? l1_b2[n] : 0.f; return; }
    if (idx < 1280)      { int n = idx - 640; bp1[n] = (n < HDIM) ? l1_b1[n] : 0.f; return; }
    { int n = idx - 1280; bp0[n] = (n < HDIM) ? l0_b1[n] : 0.f; }
}

// ---------------------------------------------------------------------------
// proj GEMM: A[64 rows] x Weff[K,640] -> UV bf16 [N,640] (bias added, no relu).
// Wave w, group g: nt = g*20 + w*5 .. +4 (group g = contiguous 320 cols).
// Epilogue: LDS bounce S[64][SSTR] -> coalesced dwordx4 stores.
// ---------------------------------------------------------------------------
template<int KS, bool A_IS_X>
__global__ __launch_bounds__(256) void proj_gemm_kernel(
    const void* __restrict__ Asrc, const unsigned short* __restrict__ PW,
    const float* __restrict__ bp,
    unsigned short* __restrict__ UV)
{
    __shared__ unsigned short As[4 * KS * 64 * 8];
    __shared__ unsigned short S[64 * SSTR];
    const int t = threadIdx.x;
    const int row0 = blockIdx.x * 64;

    if constexpr (A_IS_X) {
        const float* x = (const float*)Asrc;
        int lane = t & 63, mt = t >> 6;
        int quad = lane >> 4;
        int grow = row0 + mt * 16 + (lane & 15);
        unsigned short oz[8];
#pragma unroll
        for (int j = 0; j < 8; ++j) {
            int k = quad * 8 + j;
            oz[j] = (k < FDIM) ? f2bf(x[grow * FDIM + k]) : (unsigned short)0;
        }
        *(uint4*)(As + t * 8) = *(uint4*)oz;
    } else {
        const unsigned short* h = (const unsigned short*)Asrc;
#pragma unroll
        for (int i = 0; i < 4; ++i) {
            int s = t + 256 * i;
            int lane = s & 63;
            int ks = (s >> 6) % KS;
            int mt = s / (KS * 64);
            int grow = row0 + mt * 16 + (lane & 15);
            int k0 = ks * 32 + ((lane >> 4) << 3);
            *(uint4*)(As + s * 8) = *(const uint4*)(h + (size_t)grow * H0W + k0);
        }
    }
    __syncthreads();

    const int w = t >> 6, lane = t & 63, quad = lane >> 4, l15 = lane & 15;

    for (int g = 0; g < 2; ++g) {
        const int ntb = g * 20 + w * 5;
        floatx4 c[5][4];
#pragma unroll
        for (int i = 0; i < 5; ++i)
#pragma unroll
            for (int mt = 0; mt < 4; ++mt) c[i][mt] = (floatx4){0.f, 0.f, 0.f, 0.f};
#pragma unroll
        for (int ks = 0; ks < KS; ++ks) {
            short8 a[4];
#pragma unroll
            for (int mt = 0; mt < 4; ++mt)
                a[mt] = *(const short8*)(As + ((mt * KS + ks) * 64 + lane) * 8);
#pragma unroll
            for (int i = 0; i < 5; ++i) {
                short8 b = *(const short8*)(PW + (size_t)(((ntb + i) * KS + ks) * 64 + lane) * 8);
#pragma unroll
                for (int mt = 0; mt < 4; ++mt)
                    c[i][mt] = __builtin_amdgcn_mfma_f32_16x16x32_bf16(a[mt], b, c[i][mt], 0, 0, 0);
            }
        }
        __syncthreads();   // prev group's readout complete before overwriting S
        // scatter into S (group-local cols 0..319)
#pragma unroll
        for (int i = 0; i < 5; ++i) {
            int colp = (w * 5 + i) * 16 + l15;        // 0..319 group-local
            float bb = bp[g * 320 + colp];
#pragma unroll
            for (int mt = 0; mt < 4; ++mt) {
#pragma unroll
                for (int r = 0; r < 4; ++r) {
                    int row = mt * 16 + quad * 4 + r;
                    S[row * SSTR + colp] = f2bf(c[i][mt][r] + bb);
                }
            }
        }
        __syncthreads();
        // coalesced readout: 64 rows x 320 cols = 2560 uint4
#pragma unroll
        for (int it = 0; it < 10; ++it) {
            int s = t + 256 * it;
            int row = s / 40, c4 = s - row * 40;
            uint4 v = *(const uint4*)(S + row * SSTR + c4 * 8);
            *(uint4*)(UV + (size_t)(row0 + row) * UVW + g * 320 + c4 * 8) = v;
        }
    }
}

// ---------------------------------------------------------------------------
// Fused edge MLP + segment-max. Block = 4 nodes (M=64), 256 threads / 4 waves.
// Single-pass GEMM1 with C1 fully in registers (wave owns 5 nt x 4 mt);
// Z2 scatter REUSES Z1's LDS (41 KB total -> 3 blocks/CU); 3 barriers.
// ---------------------------------------------------------------------------
template<bool OUT_BF16>
__global__ __launch_bounds__(256, 3) void edge_mfma_kernel(
    const unsigned short* __restrict__ UV,
    const int* __restrict__ src,
    const unsigned short* __restrict__ PB2, const float* __restrict__ b2p,
    const unsigned short* __restrict__ PB3, const float* __restrict__ b3,
    void* __restrict__ hout)
{
    __shared__ unsigned short Zs[4 * KS1 * 64 * 8];   // 40960 B, Z1 then Z2

    const int t = threadIdx.x;
    const int node0 = blockIdx.x * 4;

    // ---- Z1 build: relu(U[node] + V[src]), packed-dword conversion ----
#pragma unroll
    for (int i = 0; i < 10; ++i) {
        int s = t + 256 * i;
        int lane = s & 63;
        int ks = (s >> 6) % KS1;
        int mt = s / (KS1 * 64);
        int m = mt * 16 + (lane & 15);
        int k0 = ks * 32 + ((lane >> 4) << 3);
        int srcn = src[node0 * 16 + m];
        uint4 ud = *(const uint4*)(UV + (size_t)(node0 + mt) * UVW + k0);
        uint4 vd = *(const uint4*)(UV + (size_t)srcn * UVW + HP + k0);
        unsigned o[4];
        const unsigned* up = (const unsigned*)&ud;
        const unsigned* vp = (const unsigned*)&vd;
#pragma unroll
        for (int d = 0; d < 4; ++d) {
            float ul = __uint_as_float(up[d] << 16);
            float uh = __uint_as_float(up[d] & 0xFFFF0000u);
            float vl = __uint_as_float(vp[d] << 16);
            float vh = __uint_as_float(vp[d] & 0xFFFF0000u);
            float sl = fmaxf(ul + vl, 0.f);
            float sh = fmaxf(uh + vh, 0.f);
            o[d] = packbf2(sl, sh);
        }
        *(uint4*)(Zs + s * 8) = *(uint4*)o;
    }
    __syncthreads();

    const int w = t >> 6;
    const int lane = t & 63;
    const int quad = lane >> 4;
    const int l15 = lane & 15;

    // ---- GEMM1: wave owns nt = w*5 .. w*5+4, all 4 mt, full K ----
    floatx4 c1[5][4];
#pragma unroll
    for (int i = 0; i < 5; ++i)
#pragma unroll
        for (int mt = 0; mt < 4; ++mt) c1[i][mt] = (floatx4){0.f, 0.f, 0.f, 0.f};
#pragma unroll 2
    for (int ks = 0; ks < KS1; ++ks) {
        short8 a[4];
#pragma unroll
        for (int mt = 0; mt < 4; ++mt)
            a[mt] = *(const short8*)(Zs + ((mt * KS1 + ks) * 64 + lane) * 8);
#pragma unroll
        for (int i = 0; i < 5; ++i) {
            short8 b = *(const short8*)(PB2 + (size_t)(((w * 5 + i) * KS1 + ks) * 64 + lane) * 8);
#pragma unroll
            for (int mt = 0; mt < 4; ++mt)
                c1[i][mt] = __builtin_amdgcn_mfma_f32_16x16x32_bf16(a[mt], b, c1[i][mt], 0, 0, 0);
        }
    }
    __syncthreads();   // all waves done reading Z1

    // ---- Z2 scatter into Zs (A-frag order), +b2, relu ----
#pragma unroll
    for (int i = 0; i < 5; ++i) {
        int col = (w * 5 + i) * 16 + l15;            // 0..319
        float b2v = b2p[col];
        int slotbase = (col >> 5) * 64 + (((col >> 3) & 3) << 4) + quad * 4;
        int j = col & 7;
#pragma unroll
        for (int mt = 0; mt < 4; ++mt) {
#pragma unroll
            for (int r = 0; r < 4; ++r) {
                float v = fmaxf(c1[i][mt][r] + b2v, 0.f);
                Zs[(mt * KS1 * 64 + slotbase + r) * 8 + j] = f2bf(v);
            }
        }
    }
    __syncthreads();

    // ---- GEMM2: wave owns nt2 {w*2, w*2+1} (w=3: one), all 4 mt ----
    const int cnt2 = (w < 3) ? 2 : 1;
    floatx4 c2[4][2];
#pragma unroll
    for (int mt = 0; mt < 4; ++mt)
#pragma unroll
        for (int i = 0; i < 2; ++i) c2[mt][i] = (floatx4){0.f, 0.f, 0.f, 0.f};
#pragma unroll 2
    for (int ks = 0; ks < KS2; ++ks) {
        short8 a[4];
#pragma unroll
        for (int mt = 0; mt < 4; ++mt)
            a[mt] = *(const short8*)(Zs + ((mt * KS2 + ks) * 64 + lane) * 8);
#pragma unroll
        for (int i = 0; i < 2; ++i) {
            if (i < cnt2) {
                short8 b = *(const short8*)(PB3 + (size_t)(((w * 2 + i) * KS2 + ks) * 64 + lane) * 8);
#pragma unroll
                for (int mt = 0; mt < 4; ++mt)
                    c2[mt][i] = __builtin_amdgcn_mfma_f32_16x16x32_bf16(a[mt], b, c2[mt][i], 0, 0, 0);
            }
        }
    }

    // ---- epilogue: max over 16 edge rows, +b3, relu, store ----
#pragma unroll
    for (int mt = 0; mt < 4; ++mt) {
        int node = node0 + mt;
#pragma unroll
        for (int i = 0; i < 2; ++i) {
            if (i < cnt2) {
                int col = (w * 2 + i) * 16 + l15;
                floatx4 a = c2[mt][i];
                float mx = fmaxf(fmaxf(a[0], a[1]), fmaxf(a[2], a[3]));
                mx = fmaxf(mx, __shfl_xor(mx, 16, 64));
                mx = fmaxf(mx, __shfl_xor(mx, 32, 64));
                if (quad == 0) {
                    if (OUT_BF16) {
                        unsigned short val = 0;
                        if (col < LDIM) val = f2bf(fmaxf(mx + b3[col], 0.f));
                        ((unsigned short*)hout)[(size_t)node * H0W + col] = val;
                    } else {
                        if (col < LDIM)
                            ((float*)hout)[(size_t)node * LDIM + col] = fmaxf(mx + b3[col], 0.f);
                    }
                }
            }
        }
        if (OUT_BF16 && w == 3 && quad == 0)
            ((unsigned short*)hout)[(size_t)node * H0W + 112 + l15] = 0;
    }
}

// ---------------------------------------------------------------------------
__global__ __launch_bounds__(128) void pool1_kernel(
    const float* __restrict__ h, float* __restrict__ part)
{
    int g = blockIdx.x / 25;
    int sl = blockIdx.x % 25;
    int t = threadIdx.x;
    int base = g * NPG + sl * 128;
    if (t < LDIM) {
        float s = 0.f, mx = -1e30f;
        for (int i = 0; i < 128; ++i) {
            float v = h[(size_t)(base + i) * LDIM + t];
            s += v;
            mx = fmaxf(mx, v);
        }
        part[(size_t)blockIdx.x * 200 + t] = s;
        part[(size_t)blockIdx.x * 200 + 100 + t] = mx;
    }
}

__global__ __launch_bounds__(256) void final_kernel(
    const float* __restrict__ part,
    const float* __restrict__ W1, const float* __restrict__ b1,
    const float* __restrict__ W2, const float* __restrict__ b2,
    const float* __restrict__ W3, const float* __restrict__ b3,
    float* __restrict__ out)
{
    __shared__ float P[BGRAPHS][3 * LDIM];
    __shared__ float T1[BGRAPHS][LDIM];
    __shared__ float T2[BGRAPHS][LDIM];
    int t = threadIdx.x;
    for (int i = t; i < BGRAPHS * LDIM; i += 256) {
        int g = i / LDIM, f = i - (i / LDIM) * LDIM;
        float s = 0.f, mx = -1e30f;
        for (int sl = 0; sl < 25; ++sl) {
            s += part[(size_t)(g * 25 + sl) * 200 + f];
            mx = fmaxf(mx, part[(size_t)(g * 25 + sl) * 200 + 100 + f]);
        }
        P[g][f] = s;
        P[g][LDIM + f] = s * (1.0f / NPG);
        P[g][2 * LDIM + f] = mx;
    }
    __syncthreads();
    for (int i = t; i < BGRAPHS * LDIM; i += 256) {
        int g = i / LDIM, c = i - (i / LDIM) * LDIM;
        float a = b1[c];
        for (int k = 0; k < 3 * LDIM; ++k) a = fmaf(P[g][k], W1[k * LDIM + c], a);
        T1[g][c] = fmaxf(a, 0.f);
    }
    __syncthreads();
    for (int i = t; i < BGRAPHS * LDIM; i += 256) {
        int g = i / LDIM, c = i - (i / LDIM) * LDIM;
        float a = b2[c];
        for (int k = 0; k < LDIM; ++k) a = fmaf(T1[g][k], W2[k * LDIM + c], a);
        T2[g][c] = fmaxf(a, 0.f);
    }
    __syncthreads();
    if (t < BGRAPHS) {
        float a = b3[0];
        for (int k = 0; k < LDIM; ++k) a = fmaf(T2[t][k], W3[k], a);
        out[t] = a;
    }
}

// ---------------------------------------------------------------------------
extern "C" void kernel_launch(void* const* d_in, const int* in_sizes, int n_in,
                              void* d_out, int out_size, void* d_ws, size_t ws_size,
                              hipStream_t stream)
{
    const float* x      = (const float*)d_in[0];
    const int*   src    = (const int*)d_in[1];
    const float* l0_W1  = (const float*)d_in[3];
    const float* l0_b1  = (const float*)d_in[4];
    const float* l0_W2  = (const float*)d_in[5];
    const float* l0_b2  = (const float*)d_in[6];
    const float* l0_W3  = (const float*)d_in[7];
    const float* l0_b3  = (const float*)d_in[8];
    const float* l1_W1  = (const float*)d_in[9];
    const float* l1_b1  = (const float*)d_in[10];
    const float* l1_W2  = (const float*)d_in[11];
    const float* l1_b2  = (const float*)d_in[12];
    const float* l1_W3  = (const float*)d_in[13];
    const float* l1_b3  = (const float*)d_in[14];
    const float* lin_W1 = (const float*)d_in[15];
    const float* lin_b1 = (const float*)d_in[16];
    const float* lin_W2 = (const float*)d_in[17];
    const float* lin_b2 = (const float*)d_in[18];
    const float* lin_W3 = (const float*)d_in[19];
    const float* lin_b3 = (const float*)d_in[20];
    float* out = (float*)d_out;

    char* p = (char*)d_ws;
    unsigned short* UV    = (unsigned short*)p;  p += (size_t)NNODES * UVW * 2;     // 32.77 MB
    unsigned short* h0b   = (unsigned short*)p;  p += (size_t)NNODES * H0W * 2;     // 6.55 MB
    float* h1             = (float*)p;           p += (size_t)NNODES * LDIM * 4;    // 10.24 MB
    unsigned short* PB2_0 = (unsigned short*)p;  p += (size_t)S0 * 2;
    unsigned short* PB2_1 = (unsigned short*)p;  p += (size_t)S1 * 2;
    unsigned short* PB3_0 = (unsigned short*)p;  p += (size_t)S2 * 2;
    unsigned short* PB3_1 = (unsigned short*)p;  p += (size_t)S3 * 2;
    unsigned short* PW1   = (unsigned short*)p;  p += (size_t)S4 * 2;
    unsigned short* PW0   = (unsigned short*)p;  p += (size_t)S5 * 2;
    float* b2p_0          = (float*)p;           p += HP * 4;
    float* b2p_1          = (float*)p;           p += HP * 4;
    float* bp1            = (float*)p;           p += 640 * 4;
    float* bp0            = (float*)p;           p += 640 * 4;
    float* part           = (float*)p;           p += (size_t)200 * 200 * 4;

    pack_all_kernel<<<(PACK_TOTAL + 255) / 256, 256, 0, stream>>>(
        l0_W1, l0_b1, l0_W2, l0_b2, l0_W3,
        l1_W1, l1_b1, l1_W2, l1_b2, l1_W3,
        PB2_0, PB2_1, PB3_0, PB3_1, PW1, PW0, b2p_0, b2p_1, bp1, bp0);

    // layer 0
    proj_gemm_kernel<1, true><<<NNODES / 64, 256, 0, stream>>>(x, PW0, bp0, UV);
    edge_mfma_kernel<true><<<NNODES / 4, 256, 0, stream>>>(UV, src, PB2_0, b2p_0, PB3_0, l0_b3, h0b);
    // layer 1
    proj_gemm_kernel<4, false><<<NNODES / 64, 256, 0, stream>>>(h0b, PW1, bp1, UV);
    edge_mfma_kernel<false><<<NNODES / 4, 256, 0, stream>>>(UV, src, PB2_1, b2p_1, PB3_1, l1_b3, h1);
    // pooling + head
    pool1_kernel<<<200, 128, 0, stream>>>(h1, part);
    final_kernel<<<1, 256, 0, stream>>>(part, lin_W1, lin_b1, lin_W2, lin_b2, lin_W3, lin_b3, out);
}

// Round 5
// 523.901 us; speedup vs baseline: 11.4602x; 1.0238x over previous
//
#include <hip/hip_runtime.h>

#define NNODES 25600
#define DEG 16
#define BGRAPHS 8
#define NPG (NNODES / BGRAPHS)   // 3200
#define FDIM 7
#define HDIM 300
#define LDIM 100
#define HP 320                   // padded H
#define UVW 640                  // UV row width (U 0..319 | V 320..639)
#define NT1 20                   // GEMM1 N tiles
#define KS1 10                   // GEMM1 K steps
#define NT2 7                    // GEMM2 N tiles (112 cols, >=100 masked)
#define KS2 10                   // GEMM2 K steps
#define H0W 128                  // h0 bf16 padded width
#define SSTR 328                 // proj staging row stride (shorts); 656B = 41*16

typedef __attribute__((ext_vector_type(8))) short short8;
typedef __attribute__((ext_vector_type(4))) float floatx4;

__device__ __forceinline__ float bf2f(unsigned short h) {
    return __uint_as_float(((unsigned)h) << 16);
}
__device__ __forceinline__ unsigned short f2bf(float f) {   // round-half-up (pack path)
    return (unsigned short)((__float_as_uint(f) + 0x8000u) >> 16);
}
// pack two fp32 (lo,hi) -> one dword of two bf16, round-half-up
__device__ __forceinline__ unsigned packbf2(float lo, float hi) {
    unsigned rl = __float_as_uint(lo) + 0x8000u;
    unsigned rh = __float_as_uint(hi) + 0x8000u;
    return __builtin_amdgcn_perm(rh, rl, 0x07060302);
}

// ---------------------------------------------------------------------------
// B-fragment packing: out[((nt*KS+ks)*64+lane)*8+j] = W[k][n]
// ---------------------------------------------------------------------------
__device__ __forceinline__ unsigned short packB(const float* W, int Kreal, int Nreal,
                                                int KS, int rel)
{
    int j = rel & 7, lane = (rel >> 3) & 63, rem = rel >> 9;
    int ks = rem % KS, nt = rem / KS;
    int k = ks * 32 + ((lane >> 4) << 3) + j;
    int n = nt * 16 + (lane & 15);
    float v = (k < Kreal && n < Nreal) ? W[k * Nreal + n] : 0.f;
    return f2bf(v);
}

// proj effective weights Weff[k][n], n<320 = U part (W1a - W1b), n>=320 = V part (W1b)
__device__ __forceinline__ unsigned short packProjW(const float* W1, int Ksub,
                                                    int KS, int rel)
{
    int j = rel & 7, lane = (rel >> 3) & 63, rem = rel >> 9;
    int ks = rem % KS, nt = rem / KS;
    int k = ks * 32 + ((lane >> 4) << 3) + j;
    int n = nt * 16 + (lane & 15);
    float v = 0.f;
    if (k < Ksub) {
        if (n < HP) { if (n < HDIM) v = W1[k * HDIM + n] - W1[(k + Ksub) * HDIM + n]; }
        else { int m = n - HP; if (m < HDIM) v = W1[(k + Ksub) * HDIM + m]; }
    }
    return f2bf(v);
}

#define S0 102400   // PB2_0
#define S1 102400   // PB2_1
#define S2 35840    // PB3_0
#define S3 35840    // PB3_1
#define S4 81920    // PW1 (40 nt x 4 ks)
#define S5 20480    // PW0 (40 nt x 1 ks)
#define S6 1920     // biases
#define PACK_TOTAL (S0+S1+S2+S3+S4+S5+S6)

__global__ __launch_bounds__(256) void pack_all_kernel(
    const float* __restrict__ l0_W1, const float* __restrict__ l0_b1,
    const float* __restrict__ l0_W2, const float* __restrict__ l0_b2,
    const float* __restrict__ l0_W3,
    const float* __restrict__ l1_W1, const float* __restrict__ l1_b1,
    const float* __restrict__ l1_W2, const float* __restrict__ l1_b2,
    const float* __restrict__ l1_W3,
    unsigned short* __restrict__ PB2_0, unsigned short* __restrict__ PB2_1,
    unsigned short* __restrict__ PB3_0, unsigned short* __restrict__ PB3_1,
    unsigned short* __restrict__ PW1,  unsigned short* __restrict__ PW0,
    float* __restrict__ b2p_0, float* __restrict__ b2p_1,
    float* __restrict__ bp1,   float* __restrict__ bp0)
{
    int idx = blockIdx.x * 256 + threadIdx.x;
    if (idx >= PACK_TOTAL) return;
    if (idx < S0) { PB2_0[idx] = packB(l0_W2, HDIM, HDIM, KS1, idx); return; }
    idx -= S0;
    if (idx < S1) { PB2_1[idx] = packB(l1_W2, HDIM, HDIM, KS1, idx); return; }
    idx -= S1;
    if (idx < S2) { PB3_0[idx] = packB(l0_W3, HDIM, LDIM, KS2, idx); return; }
    idx -= S2;
    if (idx < S3) { PB3_1[idx] = packB(l1_W3, HDIM, LDIM, KS2, idx); return; }
    idx -= S3;
    if (idx < S4) { PW1[idx] = packProjW(l1_W1, LDIM, 4, idx); return; }
    idx -= S4;
    if (idx < S5) { PW0[idx] = packProjW(l0_W1, FDIM, 1, idx); return; }
    idx -= S5;
    if (idx < 320)       { b2p_0[idx] = (idx < HDIM) ? l0_b2[idx] : 0.f; return; }
    if (idx < 640)       { int n = idx - 320; b2p_1[n] = (n < HDIM) ? l1_b2[n] : 0.f; return; }
    if (idx < 1280)      { int n = idx - 640; bp1[n] = (n < HDIM) ? l1_b1[n] : 0.f; return; }
    { int n = idx - 1280; bp0[n] = (n < HDIM) ? l0_b1[n] : 0.f; }
}

// ---------------------------------------------------------------------------
// proj GEMM: A[64 rows] x Weff[K,640] -> UV bf16 [N,640] (bias added, no relu).
// ---------------------------------------------------------------------------
template<int KS, bool A_IS_X>
__global__ __launch_bounds__(256) void proj_gemm_kernel(
    const void* __restrict__ Asrc, const unsigned short* __restrict__ PW,
    const float* __restrict__ bp,
    unsigned short* __restrict__ UV)
{
    __shared__ unsigned short As[4 * KS * 64 * 8];
    __shared__ unsigned short S[64 * SSTR];
    const int t = threadIdx.x;
    const int row0 = blockIdx.x * 64;

    if constexpr (A_IS_X) {
        const float* x = (const float*)Asrc;
        int lane = t & 63, mt = t >> 6;
        int quad = lane >> 4;
        int grow = row0 + mt * 16 + (lane & 15);
        unsigned short oz[8];
#pragma unroll
        for (int j = 0; j < 8; ++j) {
            int k = quad * 8 + j;
            oz[j] = (k < FDIM) ? f2bf(x[grow * FDIM + k]) : (unsigned short)0;
        }
        *(uint4*)(As + t * 8) = *(uint4*)oz;
    } else {
        const unsigned short* h = (const unsigned short*)Asrc;
#pragma unroll
        for (int i = 0; i < 4; ++i) {
            int s = t + 256 * i;
            int lane = s & 63;
            int ks = (s >> 6) % KS;
            int mt = s / (KS * 64);
            int grow = row0 + mt * 16 + (lane & 15);
            int k0 = ks * 32 + ((lane >> 4) << 3);
            *(uint4*)(As + s * 8) = *(const uint4*)(h + (size_t)grow * H0W + k0);
        }
    }
    __syncthreads();

    const int w = t >> 6, lane = t & 63, quad = lane >> 4, l15 = lane & 15;

    for (int g = 0; g < 2; ++g) {
        const int ntb = g * 20 + w * 5;
        floatx4 c[5][4];
#pragma unroll
        for (int i = 0; i < 5; ++i)
#pragma unroll
            for (int mt = 0; mt < 4; ++mt) c[i][mt] = (floatx4){0.f, 0.f, 0.f, 0.f};
#pragma unroll
        for (int ks = 0; ks < KS; ++ks) {
            short8 a[4];
#pragma unroll
            for (int mt = 0; mt < 4; ++mt)
                a[mt] = *(const short8*)(As + ((mt * KS + ks) * 64 + lane) * 8);
#pragma unroll
            for (int i = 0; i < 5; ++i) {
                short8 b = *(const short8*)(PW + (size_t)(((ntb + i) * KS + ks) * 64 + lane) * 8);
#pragma unroll
                for (int mt = 0; mt < 4; ++mt)
                    c[i][mt] = __builtin_amdgcn_mfma_f32_16x16x32_bf16(a[mt], b, c[i][mt], 0, 0, 0);
            }
        }
        __syncthreads();   // prev group's readout complete before overwriting S
#pragma unroll
        for (int i = 0; i < 5; ++i) {
            int colp = (w * 5 + i) * 16 + l15;        // 0..319 group-local
            float bb = bp[g * 320 + colp];
#pragma unroll
            for (int mt = 0; mt < 4; ++mt) {
#pragma unroll
                for (int r = 0; r < 4; ++r) {
                    int row = mt * 16 + quad * 4 + r;
                    S[row * SSTR + colp] = f2bf(c[i][mt][r] + bb);
                }
            }
        }
        __syncthreads();
#pragma unroll
        for (int it = 0; it < 10; ++it) {
            int s = t + 256 * it;
            int row = s / 40, c4 = s - row * 40;
            uint4 v = *(const uint4*)(S + row * SSTR + c4 * 8);
            *(uint4*)(UV + (size_t)(row0 + row) * UVW + g * 320 + c4 * 8) = v;
        }
    }
}

// ---------------------------------------------------------------------------
// Fused edge MLP + segment-max. Block = 4 nodes (M=64), 256 threads / 4 waves.
// Z1-build uses 64B-coalesced gather: 4 consecutive lanes read 4 consecutive
// 16B chunks of the SAME V row (full cache line). LDS Z1 layout is XOR-swizzled
// (sigma(f) = f ^ ((f&0x30)>>3)) so both the permuted dense writes and the
// GEMM1 A-reads are bank-conflict-free. Z2 path identity (unchanged).
// ---------------------------------------------------------------------------
template<bool OUT_BF16>
__global__ __launch_bounds__(256, 3) void edge_mfma_kernel(
    const unsigned short* __restrict__ UV,
    const int* __restrict__ src,
    const unsigned short* __restrict__ PB2, const float* __restrict__ b2p,
    const unsigned short* __restrict__ PB3, const float* __restrict__ b3,
    void* __restrict__ hout)
{
    __shared__ unsigned short Zs[4 * KS1 * 64 * 8];   // 40960 B, Z1 then Z2

    const int t = threadIdx.x;
    const int node0 = blockIdx.x * 4;
    const int lane = t & 63;

    // ---- Z1 build: relu(U[node] + V[src]), 64B-coalesced gather ----
    {
        const int row16 = lane >> 2;          // 0..15  (row within 16-row tile)
        const int part  = lane & 3;           // 0..3   (which 8-k chunk)
        const int fl    = row16 + 16 * part;  // A-frag lane
        const int phys  = fl ^ (part << 1);   // sigma(fl): bank-conflict-free writes
#pragma unroll
        for (int i = 0; i < 10; ++i) {
            int s = t + 256 * i;
            int ks = (s >> 6) % KS1;
            int mt = s / (KS1 * 64);
            int m = mt * 16 + row16;
            int k0 = ks * 32 + part * 8;
            int srcn = src[node0 * 16 + m];
            uint4 ud = *(const uint4*)(UV + (size_t)(node0 + mt) * UVW + k0);
            uint4 vd = *(const uint4*)(UV + (size_t)srcn * UVW + HP + k0);
            unsigned o[4];
            const unsigned* up = (const unsigned*)&ud;
            const unsigned* vp = (const unsigned*)&vd;
#pragma unroll
            for (int d = 0; d < 4; ++d) {
                float ul = __uint_as_float(up[d] << 16);
                float uh = __uint_as_float(up[d] & 0xFFFF0000u);
                float vl = __uint_as_float(vp[d] << 16);
                float vh = __uint_as_float(vp[d] & 0xFFFF0000u);
                float sl = fmaxf(ul + vl, 0.f);
                float sh = fmaxf(uh + vh, 0.f);
                o[d] = packbf2(sl, sh);
            }
            *(uint4*)(Zs + ((mt * KS1 + ks) * 64 + phys) * 8) = *(uint4*)o;
        }
    }
    __syncthreads();

    const int w = t >> 6;
    const int quad = lane >> 4;
    const int l15 = lane & 15;
    const int slane = lane ^ ((lane & 0x30) >> 3);   // sigma(lane) for Z1 reads

    // ---- GEMM1: wave owns nt = w*5 .. w*5+4, all 4 mt, full K ----
    floatx4 c1[5][4];
#pragma unroll
    for (int i = 0; i < 5; ++i)
#pragma unroll
        for (int mt = 0; mt < 4; ++mt) c1[i][mt] = (floatx4){0.f, 0.f, 0.f, 0.f};
#pragma unroll 2
    for (int ks = 0; ks < KS1; ++ks) {
        short8 a[4];
#pragma unroll
        for (int mt = 0; mt < 4; ++mt)
            a[mt] = *(const short8*)(Zs + ((mt * KS1 + ks) * 64 + slane) * 8);
#pragma unroll
        for (int i = 0; i < 5; ++i) {
            short8 b = *(const short8*)(PB2 + (size_t)(((w * 5 + i) * KS1 + ks) * 64 + lane) * 8);
#pragma unroll
            for (int mt = 0; mt < 4; ++mt)
                c1[i][mt] = __builtin_amdgcn_mfma_f32_16x16x32_bf16(a[mt], b, c1[i][mt], 0, 0, 0);
        }
    }
    __syncthreads();   // all waves done reading Z1

    // ---- Z2 scatter into Zs (A-frag order, identity), +b2, relu ----
#pragma unroll
    for (int i = 0; i < 5; ++i) {
        int col = (w * 5 + i) * 16 + l15;            // 0..319
        float b2v = b2p[col];
        int slotbase = (col >> 5) * 64 + (((col >> 3) & 3) << 4) + quad * 4;
        int j = col & 7;
#pragma unroll
        for (int mt = 0; mt < 4; ++mt) {
#pragma unroll
            for (int r = 0; r < 4; ++r) {
                float v = fmaxf(c1[i][mt][r] + b2v, 0.f);
                Zs[(mt * KS1 * 64 + slotbase + r) * 8 + j] = f2bf(v);
            }
        }
    }
    __syncthreads();

    // ---- GEMM2: wave owns nt2 {w*2, w*2+1} (w=3: one), all 4 mt ----
    const int cnt2 = (w < 3) ? 2 : 1;
    floatx4 c2[4][2];
#pragma unroll
    for (int mt = 0; mt < 4; ++mt)
#pragma unroll
        for (int i = 0; i < 2; ++i) c2[mt][i] = (floatx4){0.f, 0.f, 0.f, 0.f};
#pragma unroll 2
    for (int ks = 0; ks < KS2; ++ks) {
        short8 a[4];
#pragma unroll
        for (int mt = 0; mt < 4; ++mt)
            a[mt] = *(const short8*)(Zs + ((mt * KS2 + ks) * 64 + lane) * 8);
#pragma unroll
        for (int i = 0; i < 2; ++i) {
            if (i < cnt2) {
                short8 b = *(const short8*)(PB3 + (size_t)(((w * 2 + i) * KS2 + ks) * 64 + lane) * 8);
#pragma unroll
                for (int mt = 0; mt < 4; ++mt)
                    c2[mt][i] = __builtin_amdgcn_mfma_f32_16x16x32_bf16(a[mt], b, c2[mt][i], 0, 0, 0);
            }
        }
    }

    // ---- epilogue: max over 16 edge rows, +b3, relu, store ----
#pragma unroll
    for (int mt = 0; mt < 4; ++mt) {
        int node = node0 + mt;
#pragma unroll
        for (int i = 0; i < 2; ++i) {
            if (i < cnt2) {
                int col = (w * 2 + i) * 16 + l15;
                floatx4 a = c2[mt][i];
                float mx = fmaxf(fmaxf(a[0], a[1]), fmaxf(a[2], a[3]));
                mx = fmaxf(mx, __shfl_xor(mx, 16, 64));
                mx = fmaxf(mx, __shfl_xor(mx, 32, 64));
                if (quad == 0) {
                    if (OUT_BF16) {
                        unsigned short val = 0;
                        if (col < LDIM) val = f2bf(fmaxf(mx + b3[col], 0.f));
                        ((unsigned short*)hout)[(size_t)node * H0W + col] = val;
                    } else {
                        if (col < LDIM)
                            ((float*)hout)[(size_t)node * LDIM + col] = fmaxf(mx + b3[col], 0.f);
                    }
                }
            }
        }
        if (OUT_BF16 && w == 3 && quad == 0)
            ((unsigned short*)hout)[(size_t)node * H0W + 112 + l15] = 0;
    }
}

// ---------------------------------------------------------------------------
__global__ __launch_bounds__(128) void pool1_kernel(
    const float* __restrict__ h, float* __restrict__ part)
{
    int g = blockIdx.x / 25;
    int sl = blockIdx.x % 25;
    int t = threadIdx.x;
    int base = g * NPG + sl * 128;
    if (t < LDIM) {
        float s = 0.f, mx = -1e30f;
        for (int i = 0; i < 128; ++i) {
            float v = h[(size_t)(base + i) * LDIM + t];
            s += v;
            mx = fmaxf(mx, v);
        }
        part[(size_t)blockIdx.x * 200 + t] = s;
        part[(size_t)blockIdx.x * 200 + 100 + t] = mx;
    }
}

__global__ __launch_bounds__(256) void final_kernel(
    const float* __restrict__ part,
    const float* __restrict__ W1, const float* __restrict__ b1,
    const float* __restrict__ W2, const float* __restrict__ b2,
    const float* __restrict__ W3, const float* __restrict__ b3,
    float* __restrict__ out)
{
    __shared__ float P[BGRAPHS][3 * LDIM];
    __shared__ float T1[BGRAPHS][LDIM];
    __shared__ float T2[BGRAPHS][LDIM];
    int t = threadIdx.x;
    for (int i = t; i < BGRAPHS * LDIM; i += 256) {
        int g = i / LDIM, f = i - (i / LDIM) * LDIM;
        float s = 0.f, mx = -1e30f;
        for (int sl = 0; sl < 25; ++sl) {
            s += part[(size_t)(g * 25 + sl) * 200 + f];
            mx = fmaxf(mx, part[(size_t)(g * 25 + sl) * 200 + 100 + f]);
        }
        P[g][f] = s;
        P[g][LDIM + f] = s * (1.0f / NPG);
        P[g][2 * LDIM + f] = mx;
    }
    __syncthreads();
    for (int i = t; i < BGRAPHS * LDIM; i += 256) {
        int g = i / LDIM, c = i - (i / LDIM) * LDIM;
        float a = b1[c];
        for (int k = 0; k < 3 * LDIM; ++k) a = fmaf(P[g][k], W1[k * LDIM + c], a);
        T1[g][c] = fmaxf(a, 0.f);
    }
    __syncthreads();
    for (int i = t; i < BGRAPHS * LDIM; i += 256) {
        int g = i / LDIM, c = i - (i / LDIM) * LDIM;
        float a = b2[c];
        for (int k = 0; k < LDIM; ++k) a = fmaf(T1[g][k], W2[k * LDIM + c], a);
        T2[g][c] = fmaxf(a, 0.f);
    }
    __syncthreads();
    if (t < BGRAPHS) {
        float a = b3[0];
        for (int k = 0; k < LDIM; ++k) a = fmaf(T2[t][k], W3[k], a);
        out[t] = a;
    }
}

// ---------------------------------------------------------------------------
extern "C" void kernel_launch(void* const* d_in, const int* in_sizes, int n_in,
                              void* d_out, int out_size, void* d_ws, size_t ws_size,
                              hipStream_t stream)
{
    const float* x      = (const float*)d_in[0];
    const int*   src    = (const int*)d_in[1];
    const float* l0_W1  = (const float*)d_in[3];
    const float* l0_b1  = (const float*)d_in[4];
    const float* l0_W2  = (const float*)d_in[5];
    const float* l0_b2  = (const float*)d_in[6];
    const float* l0_W3  = (const float*)d_in[7];
    const float* l0_b3  = (const float*)d_in[8];
    const float* l1_W1  = (const float*)d_in[9];
    const float* l1_b1  = (const float*)d_in[10];
    const float* l1_W2  = (const float*)d_in[11];
    const float* l1_b2  = (const float*)d_in[12];
    const float* l1_W3  = (const float*)d_in[13];
    const float* l1_b3  = (const float*)d_in[14];
    const float* lin_W1 = (const float*)d_in[15];
    const float* lin_b1 = (const float*)d_in[16];
    const float* lin_W2 = (const float*)d_in[17];
    const float* lin_b2 = (const float*)d_in[18];
    const float* lin_W3 = (const float*)d_in[19];
    const float* lin_b3 = (const float*)d_in[20];
    float* out = (float*)d_out;

    char* p = (char*)d_ws;
    unsigned short* UV    = (unsigned short*)p;  p += (size_t)NNODES * UVW * 2;     // 32.77 MB
    unsigned short* h0b   = (unsigned short*)p;  p += (size_t)NNODES * H0W * 2;     // 6.55 MB
    float* h1             = (float*)p;           p += (size_t)NNODES * LDIM * 4;    // 10.24 MB
    unsigned short* PB2_0 = (unsigned short*)p;  p += (size_t)S0 * 2;
    unsigned short* PB2_1 = (unsigned short*)p;  p += (size_t)S1 * 2;
    unsigned short* PB3_0 = (unsigned short*)p;  p += (size_t)S2 * 2;
    unsigned short* PB3_1 = (unsigned short*)p;  p += (size_t)S3 * 2;
    unsigned short* PW1   = (unsigned short*)p;  p += (size_t)S4 * 2;
    unsigned short* PW0   = (unsigned short*)p;  p += (size_t)S5 * 2;
    float* b2p_0          = (float*)p;           p += HP * 4;
    float* b2p_1          = (float*)p;           p += HP * 4;
    float* bp1            = (float*)p;           p += 640 * 4;
    float* bp0            = (float*)p;           p += 640 * 4;
    float* part           = (float*)p;           p += (size_t)200 * 200 * 4;

    pack_all_kernel<<<(PACK_TOTAL + 255) / 256, 256, 0, stream>>>(
        l0_W1, l0_b1, l0_W2, l0_b2, l0_W3,
        l1_W1, l1_b1, l1_W2, l1_b2, l1_W3,
        PB2_0, PB2_1, PB3_0, PB3_1, PW1, PW0, b2p_0, b2p_1, bp1, bp0);

    // layer 0
    proj_gemm_kernel<1, true><<<NNODES / 64, 256, 0, stream>>>(x, PW0, bp0, UV);
    edge_mfma_kernel<true><<<NNODES / 4, 256, 0, stream>>>(UV, src, PB2_0, b2p_0, PB3_0, l0_b3, h0b);
    // layer 1
    proj_gemm_kernel<4, false><<<NNODES / 64, 256, 0, stream>>>(h0b, PW1, bp1, UV);
    edge_mfma_kernel<false><<<NNODES / 4, 256, 0, stream>>>(UV, src, PB2_1, b2p_1, PB3_1, l1_b3, h1);
    // pooling + head
    pool1_kernel<<<200, 128, 0, stream>>>(h1, part);
    final_kernel<<<1, 256, 0, stream>>>(part, lin_W1, lin_b1, lin_W2, lin_b2, lin_W3, lin_b3, out);
}